// Round 14
// baseline (540.686 us; speedup 1.0000x reference)
//
#include <hip/hip_runtime.h>
#include <hip/hip_bf16.h>

// Problem constants
#define B_DIM 4096
#define H_DIM 1024
#define K1    2048   // IN + H
#define N1    6144   // 5 gates * 1024 + a1 (1024)

typedef __attribute__((ext_vector_type(8))) short bf16x8;
typedef __attribute__((ext_vector_type(4))) float f32x4;

__device__ __forceinline__ unsigned short f2bf(float f) {
  unsigned int x = __float_as_uint(f);
  x += 0x7fffu + ((x >> 16) & 1u);   // RTNE
  return (unsigned short)(x >> 16);
}
__device__ __forceinline__ float bf2f(unsigned short u) {
  return __uint_as_float(((unsigned int)u) << 16);
}
__device__ __forceinline__ float fast_sigmoid(float x) {
  return __builtin_amdgcn_rcpf(1.0f + __expf(-x));
}
__device__ __forceinline__ float fast_tanh(float x) {
  return 1.0f - 2.0f * __builtin_amdgcn_rcpf(1.0f + __expf(2.0f * x));
}
__device__ __forceinline__ void gload_lds16(const void* g, void* l) {
  __builtin_amdgcn_global_load_lds(
      (const __attribute__((address_space(1))) void*)g,
      (__attribute__((address_space(3))) void*)l, 16, 0, 0);
}

// m201's st_16x32 swizzle: XOR byte-bit5 with bit9 within a 1024B subtile.
__device__ __forceinline__ int swz1k(int x) {
  return x ^ (((x >> 9) & 1) << 5);
}

// ---------------------------------------------------------------------------
// prep: build bf16 activations + weight panels in workspace (grid-stride vec4)
// ---------------------------------------------------------------------------
__global__ __launch_bounds__(256) void prep_kernel(
    const float* __restrict__ x, const float* __restrict__ h,
    const float* __restrict__ ssg_state,
    const float* __restrict__ Wx, const float* __restrict__ Ux,
    const float* __restrict__ a1_w,
    const float* __restrict__ ssg_w, const float* __restrict__ r1_w,
    const float* __restrict__ r2_w, const float* __restrict__ r3_w,
    unsigned short* __restrict__ combined,
    unsigned short* __restrict__ ssg_in,
    unsigned short* __restrict__ W1,
    unsigned short* __restrict__ W2,
    unsigned short* __restrict__ W3,
    unsigned short* __restrict__ W4)
{
  const size_t NV0 = (size_t)B_DIM * K1 / 4;      // combined
  const size_t NV1 = (size_t)B_DIM * H_DIM / 4;   // ssg_in
  const size_t NV3 = (size_t)N1 * K1 / 4;         // W1
  const size_t NV4 = (size_t)2048 * H_DIM / 4;    // W2
  const size_t NV5 = (size_t)H_DIM * H_DIM / 4;   // W3, W4
  const size_t total = NV0 + NV1 + NV3 + NV4 + NV5 + NV5;
  const size_t stride = (size_t)gridDim.x * blockDim.x;

  for (size_t v = (size_t)blockIdx.x * blockDim.x + threadIdx.x; v < total; v += stride) {
    size_t idx = v;
    const float* src;
    unsigned short* dst;
    if (idx < NV0) {
      size_t e = idx * 4, b = e >> 11, k = e & 2047;
      src = (k < 1024) ? &x[(b << 10) + k] : &h[(b << 10) + (k - 1024)];
      dst = &combined[e];
    } else if ((idx -= NV0) < NV1) {
      size_t e = idx * 4;
      float4 a = *(const float4*)&ssg_state[e];
      float4 c = *(const float4*)&h[e];
      ushort4 o;
      o.x = f2bf(a.x + c.x); o.y = f2bf(a.y + c.y);
      o.z = f2bf(a.z + c.z); o.w = f2bf(a.w + c.w);
      *(ushort4*)&ssg_in[e] = o;
      continue;
    } else if ((idx -= NV1) < NV3) {
      size_t e = idx * 4, n = e >> 11, k = e & 2047;
      if (n < 5120) src = (k < 1024) ? &Wx[(n << 10) + k] : &Ux[(n << 10) + (k - 1024)];
      else          src = &a1_w[((n - 5120) << 11) + k];
      dst = &W1[e];
    } else if ((idx -= NV3) < NV4) {
      size_t e = idx * 4, n = e >> 10, k = e & 1023;
      src = (n < 1024) ? &ssg_w[(n << 10) + k] : &r1_w[((n - 1024) << 10) + k];
      dst = &W2[e];
    } else if ((idx -= NV4) < NV5) {
      size_t e = idx * 4; src = &r2_w[e]; dst = &W3[e];
    } else {
      idx -= NV5;
      size_t e = idx * 4; src = &r3_w[e]; dst = &W4[e];
    }
    float4 a = *(const float4*)src;
    ushort4 o;
    o.x = f2bf(a.x); o.y = f2bf(a.y); o.z = f2bf(a.z); o.w = f2bf(a.w);
    *(ushort4*)dst = o;
  }
}

// ---------------------------------------------------------------------------
// body192_bk32: 128x192 tile, BK=32, 4 waves 2x2 (per-wave 64x96, 4x6 frags,
// 24 MFMA/K-tile), 1-barrier K-tile schedule, 40 KB LDS -> 4 blocks/CU
// (16 waves/CU; this round's experiment: does 2x TLP hide the per-tile
// vmcnt(0)+barrier drain?). Same swizzle/subtile layout as R12 (1KB 16x32).
// ---------------------------------------------------------------------------
__device__ __forceinline__ void body192_bk32(
    unsigned short* lds, const int bid,
    const unsigned short* __restrict__ A,
    const unsigned short* __restrict__ W,
    const float* __restrict__ bWx, const float* __restrict__ bUx,
    const float* __restrict__ a1_b,
    unsigned short* __restrict__ gates,
    unsigned short* __restrict__ a_hidden)
{
  constexpr int NT  = 64;       // K = 2048, BK = 32
  constexpr int NTN = 32;       // 6144 / 192
  constexpr int NWG = 32 * NTN; // 1024

  const int tid  = threadIdx.x;
  const int wave = tid >> 6;
  const int lane = tid & 63;
  const int wm = wave >> 1;     // row half (64)
  const int wn = wave & 1;      // col half (96)

  const int swz = (bid & 7) * (NWG / 8) + (bid >> 3);
  const int tm = swz / NTN, tn = swz % NTN;
  const int tmB = tm * 128, tnB = tn * 192;

  // ---- stage source addressing (pre-swizzled source, linear dest) ----
  const int sidx = swz1k(lane * 16);
  const int r_l  = sidx >> 6;          // row 0..15 within subtile
  const int kel  = (sidx & 63) >> 1;   // k elem 0..31 (mult of 8)
  const unsigned short* pA[2];
  const unsigned short* pB[3];
#pragma unroll
  for (int rg = 0; rg < 2; ++rg)
    pA[rg] = A + (size_t)(tmB + (wave * 2 + rg) * 16 + r_l) * K1 + kel;
#pragma unroll
  for (int rg = 0; rg < 3; ++rg)
    pB[rg] = W + (size_t)(tnB + (wave * 3 + rg) * 16 + r_l) * K1 + kel;

  // LDS shorts: buffer p at p*10240 (20KB). A: 8 subtiles (4096 shorts);
  // B: 12 subtiles at +4096.
#define STAGE_A(tt) do { const int p_ = (tt) & 1;                                \
    _Pragma("unroll")                                                            \
    for (int rg = 0; rg < 2; ++rg)                                               \
      gload_lds16(pA[rg] + (size_t)(tt) * 32,                                    \
                  &lds[p_ * 10240 + (wave * 2 + rg) * 512]);                     \
  } while (0)
#define STAGE_B(tt) do { const int p_ = (tt) & 1;                                \
    _Pragma("unroll")                                                            \
    for (int rg = 0; rg < 3; ++rg)                                               \
      gload_lds16(pB[rg] + (size_t)(tt) * 32,                                    \
                  &lds[p_ * 10240 + 4096 + (wave * 3 + rg) * 512]);              \
  } while (0)

  const int loc = swz1k((lane & 15) * 64 + (lane >> 4) * 16);

  f32x4 acc[4][6];
#pragma unroll
  for (int m = 0; m < 4; ++m)
#pragma unroll
    for (int n = 0; n < 6; ++n) acc[m][n] = (f32x4){0.f, 0.f, 0.f, 0.f};

  STAGE_A(0); STAGE_B(0);   // 5 vmem ops/wave

  const char* lchar = (const char*)lds;
  for (int t = 0; t < NT; ++t) {
    asm volatile("s_waitcnt vmcnt(0)" ::: "memory");
    __builtin_amdgcn_s_barrier();

    const char* base = lchar + (t & 1) * 20480;
    const char* bA = base + wm * 4096 + loc;           // 4 subtiles
    const char* bB = base + 8192 + wn * 6144 + loc;    // 6 subtiles

    bf16x8 av[4], bv[6];
#pragma unroll
    for (int n = 0; n < 6; ++n) bv[n] = *(const bf16x8*)(bB + n * 1024);
#pragma unroll
    for (int m = 0; m < 4; ++m) av[m] = *(const bf16x8*)(bA + m * 1024);
    if (t + 1 < NT) { STAGE_A(t + 1); STAGE_B(t + 1); }

    __builtin_amdgcn_s_setprio(1);
#pragma unroll
    for (int n = 0; n < 6; ++n)
#pragma unroll
      for (int m = 0; m < 4; ++m)
        acc[m][n] = __builtin_amdgcn_mfma_f32_16x16x32_bf16(av[m], bv[n],
                                                            acc[m][n], 0, 0, 0);
    __builtin_amdgcn_s_setprio(0);
  }
#undef STAGE_A
#undef STAGE_B

  // ---- epilogue (R12-verified): per-wave 3KB slab -> coalesced 16B stores
  unsigned short* slab = &lds[wave * 1536];
  const int l15 = lane & 15, lq4 = (lane >> 4) << 2;
  const int colg0 = tnB + wn * 96;
  const int rowg0 = tmB + wm * 64;
  const size_t BH = (size_t)B_DIM * H_DIM;

  float biasv[6];
  int amode[6];   // 0 sigmoid, 1 tanh, 2 relu
#pragma unroll
  for (int fn = 0; fn < 6; ++fn) {
    const int c = colg0 + fn * 16 + l15;
    if (c < 5120) {
      biasv[fn] = bWx[c] + bUx[c];
      amode[fn] = ((c >> 10) == 3) ? 1 : 0;
    } else {
      biasv[fn] = a1_b[c - 5120];
      amode[fn] = 2;
    }
  }
  __builtin_amdgcn_s_barrier();
#pragma unroll
  for (int fm = 0; fm < 4; ++fm) {
#pragma unroll
    for (int fn = 0; fn < 6; ++fn) {
      f32x4 v = acc[fm][fn];
#pragma unroll
      for (int j = 0; j < 4; ++j) {
        const int row = lq4 + j;
        const float xv = v[j] + biasv[fn];
        const float res = (amode[fn] == 1) ? fast_tanh(xv)
                         : (amode[fn] == 0) ? fast_sigmoid(xv)
                         : fmaxf(xv, 0.f);
        const int byte = (row * 192 + (fn * 16 + l15) * 2) ^ (((row >> 2) & 1) << 5);
        slab[byte >> 1] = f2bf(res);
      }
    }
    asm volatile("s_waitcnt lgkmcnt(0)" ::: "memory");
    __builtin_amdgcn_sched_barrier(0);
#pragma unroll
    for (int p = 0; p < 3; ++p) {
      const int id = p * 64 + lane;
      const int row = id / 12, cc = id - row * 12;
      const int byte = (row * 192 + cc * 16) ^ (((row >> 2) & 1) << 5);
      bf16x8 pk = *(const bf16x8*)((const char*)slab + byte);
      const int col = colg0 + cc * 8;
      const size_t r = (size_t)(rowg0 + fm * 16 + row);
      unsigned short* dst;
      if (col < 5120) dst = gates + (size_t)(col >> 10) * BH + r * 1024 + (col & 1023);
      else            dst = a_hidden + r * 1024 + (col - 5120);
      *(bf16x8*)dst = pk;
    }
    asm volatile("s_waitcnt lgkmcnt(0)" ::: "memory");
    __builtin_amdgcn_sched_barrier(0);
  }
}

// ---------------------------------------------------------------------------
// body128_bk32 (seg-1, ssg+r1): 128x128 tile, BK=32, 32 KB LDS. Same schedule.
// tn<8: A0 lda1024 -> ssg fp32; tn>=8: A1 lda2048 -> r1 relu bf16.
// ---------------------------------------------------------------------------
__device__ __forceinline__ void body128_bk32(
    unsigned short* lds, const int bid,
    const unsigned short* __restrict__ A0,
    const unsigned short* __restrict__ A1,
    const unsigned short* __restrict__ W,
    const float* __restrict__ b0, const float* __restrict__ b1,
    float* __restrict__ out0, unsigned short* __restrict__ out1)
{
  constexpr int NT  = 32;   // K = 1024, BK = 32
  constexpr int NTN = 16;
  constexpr int NWG = 32 * NTN;

  const int tid  = threadIdx.x;
  const int wave = tid >> 6;
  const int lane = tid & 63;
  const int wm = wave >> 1;
  const int wn = wave & 1;

  const int swz = (bid & 7) * (NWG / 8) + (bid >> 3);
  const int tm = swz / NTN, tn = swz % NTN;
  const int tmB = tm * 128, tnB = tn * 128;

  const unsigned short* Abase = A0;
  int lda = 1024;
  if (tn >= 8) { Abase = A1; lda = 2048; }

  const int sidx = swz1k(lane * 16);
  const int r_l  = sidx >> 6;
  const int kel  = (sidx & 63) >> 1;
  const unsigned short* pA[2];
  const unsigned short* pB[2];
#pragma unroll
  for (int rg = 0; rg < 2; ++rg) {
    pA[rg] = Abase + (size_t)(tmB + (wave * 2 + rg) * 16 + r_l) * lda + kel;
    pB[rg] = W + (size_t)(tnB + (wave * 2 + rg) * 16 + r_l) * 1024 + kel;
  }

  // buffer p at p*8192 shorts (16KB); A 8 subtiles, B 8 at +4096.
#define STAGE_A(tt) do { const int p_ = (tt) & 1;                                \
    _Pragma("unroll")                                                            \
    for (int rg = 0; rg < 2; ++rg)                                               \
      gload_lds16(pA[rg] + (size_t)(tt) * 32,                                    \
                  &lds[p_ * 8192 + (wave * 2 + rg) * 512]);                      \
  } while (0)
#define STAGE_B(tt) do { const int p_ = (tt) & 1;                                \
    _Pragma("unroll")                                                            \
    for (int rg = 0; rg < 2; ++rg)                                               \
      gload_lds16(pB[rg] + (size_t)(tt) * 32,                                    \
                  &lds[p_ * 8192 + 4096 + (wave * 2 + rg) * 512]);               \
  } while (0)

  const int loc = swz1k((lane & 15) * 64 + (lane >> 4) * 16);

  f32x4 acc[4][4];
#pragma unroll
  for (int m = 0; m < 4; ++m)
#pragma unroll
    for (int n = 0; n < 4; ++n) acc[m][n] = (f32x4){0.f, 0.f, 0.f, 0.f};

  STAGE_A(0); STAGE_B(0);

  const char* lchar = (const char*)lds;
  for (int t = 0; t < NT; ++t) {
    asm volatile("s_waitcnt vmcnt(0)" ::: "memory");
    __builtin_amdgcn_s_barrier();

    const char* base = lchar + (t & 1) * 16384;
    const char* bA = base + wm * 4096 + loc;
    const char* bB = base + 8192 + wn * 4096 + loc;

    bf16x8 av[4], bv[4];
#pragma unroll
    for (int n = 0; n < 4; ++n) bv[n] = *(const bf16x8*)(bB + n * 1024);
#pragma unroll
    for (int m = 0; m < 4; ++m) av[m] = *(const bf16x8*)(bA + m * 1024);
    if (t + 1 < NT) { STAGE_A(t + 1); STAGE_B(t + 1); }

    __builtin_amdgcn_s_setprio(1);
#pragma unroll
    for (int n = 0; n < 4; ++n)
#pragma unroll
      for (int m = 0; m < 4; ++m)
        acc[m][n] = __builtin_amdgcn_mfma_f32_16x16x32_bf16(av[m], bv[n],
                                                            acc[m][n], 0, 0, 0);
    __builtin_amdgcn_s_setprio(0);
  }
#undef STAGE_A
#undef STAGE_B

  const int l15 = lane & 15, lq4 = (lane >> 4) << 2;
  const int rowg0 = tmB + wm * 64;

  if (tn < 8) {
    const int col0 = tn * 128 + wn * 64;
#pragma unroll
    for (int fn = 0; fn < 4; ++fn) {
      const int col = col0 + fn * 16 + l15;
      const float bias = b0[col];
#pragma unroll
      for (int fm = 0; fm < 4; ++fm) {
        f32x4 v = acc[fm][fn];
#pragma unroll
        for (int j = 0; j < 4; ++j) {
          const int r = rowg0 + fm * 16 + lq4 + j;
          out0[(size_t)r * 1024 + col] = v[j] + bias;
        }
      }
    }
    return;
  }

  unsigned short* slab = &lds[wave * 1024];
  const int lr8 = lane >> 3, lc8 = lane & 7;
  const int colg0 = (tn - 8) * 128 + wn * 64;
  float biasv[4];
#pragma unroll
  for (int fn = 0; fn < 4; ++fn) biasv[fn] = b1[colg0 + fn * 16 + l15];
  __builtin_amdgcn_s_barrier();
#pragma unroll
  for (int fm = 0; fm < 4; ++fm) {
#pragma unroll
    for (int fn = 0; fn < 4; ++fn) {
      f32x4 v = acc[fm][fn];
#pragma unroll
      for (int j = 0; j < 4; ++j) {
        const int row = lq4 + j;
        const float res = fmaxf(v[j] + biasv[fn], 0.f);
        const int colb = ((fn * 16 + l15) * 2) ^ (((row >> 2) & 3) << 5);
        slab[(row * 128 + colb) >> 1] = f2bf(res);
      }
    }
    asm volatile("s_waitcnt lgkmcnt(0)" ::: "memory");
    __builtin_amdgcn_sched_barrier(0);
#pragma unroll
    for (int rd = 0; rd < 2; ++rd) {
      const int row = rd * 8 + lr8;
      const int cb = (lc8 * 16) ^ (((row >> 2) & 3) << 5);
      bf16x8 pk = *(const bf16x8*)((const char*)slab + row * 128 + cb);
      const size_t r = (size_t)(rowg0 + fm * 16 + row);
      *(bf16x8*)&out1[r * 1024 + colg0 + lc8 * 8] = pk;
    }
    asm volatile("s_waitcnt lgkmcnt(0)" ::: "memory");
    __builtin_amdgcn_sched_barrier(0);
  }
}

// ---------------------------------------------------------------------------
// merged big GEMM: blocks [0,1024) = gates+a_hidden (128x192 BK32);
// [1024,1536) = ssg+r1 (128x128 BK32). 40 KB LDS -> 4 blocks/CU.
// ---------------------------------------------------------------------------
__global__ __launch_bounds__(256, 4) void gemm_big(
    const unsigned short* __restrict__ combined,
    const unsigned short* __restrict__ ssg_in,
    const unsigned short* __restrict__ W1,
    const unsigned short* __restrict__ W2,
    const float* __restrict__ bWx, const float* __restrict__ bUx,
    const float* __restrict__ a1_b,
    const float* __restrict__ ssg_b, const float* __restrict__ r1_b,
    unsigned short* __restrict__ gates,
    unsigned short* __restrict__ a_hidden,
    float* __restrict__ ssg_out,
    unsigned short* __restrict__ r1)
{
  __shared__ unsigned short lds[20480];  // 40 KiB
  const int bid = blockIdx.x;
  if (bid < 1024) {
    body192_bk32(lds, bid, combined, W1, bWx, bUx, a1_b, gates, a_hidden);
  } else {
    body128_bk32(lds, bid - 1024, ssg_in, combined + 1024, W2,
                 ssg_b, r1_b, ssg_out, r1);
  }
}

// ---------------------------------------------------------------------------
// gemm_small64<MODE>: 64x128 tile, BK=64, 48 KB LDS, 3 blocks/CU, grid 512.
// R13-verified, unchanged. MODE 2: relu->bf16. MODE 3: fp32+bias.
// ---------------------------------------------------------------------------
template <int MODE>
__global__ __launch_bounds__(256, 3) void gemm_small64(
    const unsigned short* __restrict__ A,
    const unsigned short* __restrict__ W,
    const float* __restrict__ bias,
    void* __restrict__ out)
{
  __shared__ unsigned short lds[24576];
  constexpr int NT = 16;

  const int tid  = threadIdx.x;
  const int wave = tid >> 6;
  const int lane = tid & 63;
  const int wm = wave >> 1;
  const int wn = wave & 1;

  const int bid = blockIdx.x;
  const int swz = (bid & 7) * 64 + (bid >> 3);
  const int tm = swz >> 3, tn = swz & 7;
  const int tmB = tm * 64, tnB = tn * 128;

  const int sidx = swz1k(lane * 16);
  const int r_l  = sidx >> 6;
  const int kel  = (sidx & 63) >> 1;
  const unsigned short* pA[2];
  const unsigned short* pB[2][2];
#pragma unroll
  for (int j = 0; j < 2; ++j)
    pA[j] = A + (size_t)(tmB + wave * 16 + r_l) * 1024 + j * 32 + kel;
#pragma unroll
  for (int rg = 0; rg < 2; ++rg)
#pragma unroll
    for (int j = 0; j < 2; ++j)
      pB[rg][j] = W + (size_t)(tnB + (wave * 2 + rg) * 16 + r_l) * 1024 + j * 32 + kel;

#define STAGE_A(tt) do { const int p_ = (tt) & 1;                                \
    _Pragma("unroll")                                                            \
    for (int j = 0; j < 2; ++j)                                                  \
      gload_lds16(pA[j] + (size_t)(tt) * 64,                                     \
                  &lds[p_ * 12288 + (wave * 2 + j) * 512]);                      \
  } while (0)
#define STAGE_B(tt) do { const int p_ = (tt) & 1;                                \
    _Pragma("unroll")                                                            \
    for (int rg = 0; rg < 2; ++rg)                                               \
      _Pragma("unroll")                                                          \
      for (int j = 0; j < 2; ++j)                                                \
        gload_lds16(pB[rg][j] + (size_t)(tt) * 64,                               \
                    &lds[p_ * 12288 + 4096 + ((wave * 2 + rg) * 2 + j) * 512]);  \
  } while (0)

  const int loc = swz1k((lane & 15) * 64 + (lane >> 4) * 16);

  f32x4 acc[2][4];
#pragma unroll
  for (int m = 0; m < 2; ++m)
#pragma unroll
    for (int n = 0; n < 4; ++n) acc[m][n] = (f32x4){0.f, 0.f, 0.f, 0.f};

  STAGE_A(0); STAGE_B(0);

  const char* lchar = (const char*)lds;
  for (int t = 0; t < NT; ++t) {
    asm volatile("s_waitcnt vmcnt(0)" ::: "memory");
    __builtin_amdgcn_s_barrier();

    const char* base = lchar + (t & 1) * 24576;
    const char* bA = base + wm * 4096 + loc;
    const char* bB = base + 8192 + wn * 8192 + loc;

    bf16x8 a0[2], a1[2], b0[4], b1[4];
#pragma unroll
    for (int n = 0; n < 4; ++n) b0[n] = *(const bf16x8*)(bB + (2 * n + 0) * 1024);
#pragma unroll
    for (int m = 0; m < 2; ++m) a0[m] = *(const bf16x8*)(bA + (2 * m + 0) * 1024);
    if (t + 1 < NT) STAGE_A(t + 1);
#pragma unroll
    for (int n = 0; n < 4; ++n) b1[n] = *(const bf16x8*)(bB + (2 * n + 1) * 1024);
#pragma unroll
    for (int m = 0; m < 2; ++m) a1[m] = *(const bf16x8*)(bA + (2 * m + 1) * 1024);
    if (t + 1 < NT) STAGE_B(t + 1);

    __builtin_amdgcn_s_setprio(1);
#pragma unroll
    for (int n = 0; n < 4; ++n)
#pragma unroll
      for (int m = 0; m < 2; ++m)
        acc[m][n] = __builtin_amdgcn_mfma_f32_16x16x32_bf16(a0[m], b0[n], acc[m][n], 0, 0, 0);
    __builtin_amdgcn_s_setprio(0);
    __builtin_amdgcn_s_setprio(1);
#pragma unroll
    for (int n = 0; n < 4; ++n)
#pragma unroll
      for (int m = 0; m < 2; ++m)
        acc[m][n] = __builtin_amdgcn_mfma_f32_16x16x32_bf16(a1[m], b1[n], acc[m][n], 0, 0, 0);
    __builtin_amdgcn_s_setprio(0);
  }
#undef STAGE_A
#undef STAGE_B

  const int l15 = lane & 15, lq4 = (lane >> 4) << 2;
  const int rowg0 = tmB + wm * 32;

  if (MODE == 3) {
    const int col0 = tnB + wn * 64;
#pragma unroll
    for (int fn = 0; fn < 4; ++fn) {
      const int col = col0 + fn * 16 + l15;
      const float bv = bias[col];
#pragma unroll
      for (int fm = 0; fm < 2; ++fm) {
        f32x4 v = acc[fm][fn];
#pragma unroll
        for (int j = 0; j < 4; ++j) {
          const int r = rowg0 + fm * 16 + lq4 + j;
          ((float*)out)[(size_t)r * 1024 + col] = v[j] + bv;
        }
      }
    }
    return;
  }

  unsigned short* slab = &lds[wave * 1024];
  const int lr8 = lane >> 3, lc8 = lane & 7;
  const int colg0 = tnB + wn * 64;
  unsigned short* outbase = (unsigned short*)out;
  float biasv[4];
#pragma unroll
  for (int fn = 0; fn < 4; ++fn) biasv[fn] = bias[colg0 + fn * 16 + l15];
  __builtin_amdgcn_s_barrier();
#pragma unroll
  for (int fm = 0; fm < 2; ++fm) {
#pragma unroll
    for (int fn = 0; fn < 4; ++fn) {
      f32x4 v = acc[fm][fn];
#pragma unroll
      for (int j = 0; j < 4; ++j) {
        const int row = lq4 + j;
        const float res = fmaxf(v[j] + biasv[fn], 0.f);
        const int colb = ((fn * 16 + l15) * 2) ^ (((row >> 2) & 3) << 5);
        slab[(row * 128 + colb) >> 1] = f2bf(res);
      }
    }
    asm volatile("s_waitcnt lgkmcnt(0)" ::: "memory");
    __builtin_amdgcn_sched_barrier(0);
#pragma unroll
    for (int rd = 0; rd < 2; ++rd) {
      const int row = rd * 8 + lr8;
      const int cb = (lc8 * 16) ^ (((row >> 2) & 3) << 5);
      bf16x8 pk = *(const bf16x8*)((const char*)slab + row * 128 + cb);
      const size_t r = (size_t)(rowg0 + fm * 16 + row);
      *(bf16x8*)&outbase[r * 1024 + colg0 + lc8 * 8] = pk;
    }
    asm volatile("s_waitcnt lgkmcnt(0)" ::: "memory");
    __builtin_amdgcn_sched_barrier(0);
  }
}

// ---------------------------------------------------------------------------
// final fused: per-row alpha (4-wave reduce) + vec4 elementwise cell update.
// ---------------------------------------------------------------------------
__global__ __launch_bounds__(256) void final_fused(
    const unsigned short* __restrict__ gates,
    const float* __restrict__ c_prev,
    const unsigned short* __restrict__ a_hidden,
    const float* __restrict__ a2_w, const float* __restrict__ a2_b,
    const float* __restrict__ residual,
    const float* __restrict__ ssg_new,
    float* __restrict__ h_out, float* __restrict__ c_out)
{
  __shared__ float red[5];
  const int r = blockIdx.x;
  const int tid = threadIdx.x;
  const size_t BH = (size_t)B_DIM * H_DIM;

  {
    ushort4 u = *(const ushort4*)&a_hidden[(size_t)r * 1024 + tid * 4];
    float4 w = *(const float4*)&a2_w[tid * 4];
    float s = bf2f(u.x) * w.x + bf2f(u.y) * w.y + bf2f(u.z) * w.z + bf2f(u.w) * w.w;
#pragma unroll
    for (int off = 32; off; off >>= 1) s += __shfl_xor(s, off);
    if ((tid & 63) == 0) red[tid >> 6] = s;
  }
  __syncthreads();
  if (tid == 0)
    red[4] = fast_sigmoid(red[0] + red[1] + red[2] + red[3] + a2_b[0]);
  __syncthreads();
  const float al = red[4];

  const size_t e = (size_t)r * 1024 + tid * 4;
  ushort4 iu = *(const ushort4*)&gates[e];
  ushort4 fu = *(const ushort4*)&gates[BH + e];
  ushort4 ou = *(const ushort4*)&gates[2 * BH + e];
  ushort4 cu = *(const ushort4*)&gates[3 * BH + e];
  ushort4 su = *(const ushort4*)&gates[4 * BH + e];
  float4 cp = *(const float4*)&c_prev[e];
  float4 rs = *(const float4*)&residual[e];
  float4 sg = *(const float4*)&ssg_new[e];
  float4 ho, co;
  co.x = bf2f(fu.x) * cp.x + bf2f(iu.x) * bf2f(cu.x) * bf2f(su.x) * al * sg.x + rs.x;
  co.y = bf2f(fu.y) * cp.y + bf2f(iu.y) * bf2f(cu.y) * bf2f(su.y) * al * sg.y + rs.y;
  co.z = bf2f(fu.z) * cp.z + bf2f(iu.z) * bf2f(cu.z) * bf2f(su.z) * al * sg.z + rs.z;
  co.w = bf2f(fu.w) * cp.w + bf2f(iu.w) * bf2f(cu.w) * bf2f(su.w) * al * sg.w + rs.w;
  ho.x = bf2f(ou.x) * fast_tanh(co.x);
  ho.y = bf2f(ou.y) * fast_tanh(co.y);
  ho.z = bf2f(ou.z) * fast_tanh(co.z);
  ho.w = bf2f(ou.w) * fast_tanh(co.w);
  *(float4*)&h_out[e] = ho;
  *(float4*)&c_out[e] = co;
}

// ---------------------------------------------------------------------------
extern "C" void kernel_launch(void* const* d_in, const int* in_sizes, int n_in,
                              void* d_out, int out_size, void* d_ws, size_t ws_size,
                              hipStream_t stream)
{
  (void)in_sizes; (void)n_in; (void)out_size; (void)ws_size;
  const float* x         = (const float*)d_in[0];
  const float* h_prev    = (const float*)d_in[1];
  const float* c_prev    = (const float*)d_in[2];
  const float* ssg_state = (const float*)d_in[3];
  const float* Wx        = (const float*)d_in[4];
  const float* bWx       = (const float*)d_in[5];
  const float* Ux        = (const float*)d_in[6];
  const float* bUx       = (const float*)d_in[7];
  const float* a1_w      = (const float*)d_in[8];
  const float* a1_b      = (const float*)d_in[9];
  const float* a2_w      = (const float*)d_in[10];
  const float* a2_b      = (const float*)d_in[11];
  const float* r1_w      = (const float*)d_in[12];
  const float* r1_b      = (const float*)d_in[13];
  const float* r2_w      = (const float*)d_in[14];
  const float* r2_b      = (const float*)d_in[15];
  const float* r3_w      = (const float*)d_in[16];
  const float* r3_b      = (const float*)d_in[17];
  const float* ssg_w     = (const float*)d_in[18];
  const float* ssg_b     = (const float*)d_in[19];

  char* ws = (char*)d_ws;
  unsigned short* combined = (unsigned short*)(ws);               // 16,777,216
  unsigned short* ssg_in   = (unsigned short*)(ws + 16777216);    //  8,388,608
  unsigned short* W1       = (unsigned short*)(ws + 33554432);    // 25,165,824
  unsigned short* W2       = (unsigned short*)(ws + 58720256);    //  4,194,304
  unsigned short* W3       = (unsigned short*)(ws + 62914560);    //  2,097,152
  unsigned short* W4       = (unsigned short*)(ws + 65011712);    //  2,097,152
  unsigned short* gates    = (unsigned short*)(ws + 67108864);    // 41,943,040
  unsigned short* a_hidden = (unsigned short*)(ws + 109051904);   //  8,388,608
  unsigned short* r1       = (unsigned short*)(ws + 117456896);   //  8,388,608
  unsigned short* r2       = (unsigned short*)(ws + 125845504);   //  8,388,608
  float*          residual = (float*)(ws + 134234112);            // 16,777,216

  float* h_out   = (float*)d_out;
  float* c_out   = h_out + (size_t)B_DIM * H_DIM;
  float* ssg_out = c_out + (size_t)B_DIM * H_DIM;

  prep_kernel<<<4096, 256, 0, stream>>>(x, h_prev, ssg_state, Wx, Ux, a1_w,
                                        ssg_w, r1_w, r2_w, r3_w,
                                        combined, ssg_in, W1, W2, W3, W4);

  gemm_big<<<1536, 256, 0, stream>>>(
      combined, ssg_in, W1, W2, bWx, bUx, a1_b, ssg_b, r1_b,
      gates, a_hidden, ssg_out, r1);

  gemm_small64<2><<<512, 256, 0, stream>>>(r1, W3, r2_b, r2);

  gemm_small64<3><<<512, 256, 0, stream>>>(r2, W4, r3_b, residual);

  final_fused<<<B_DIM, 256, 0, stream>>>(
      gates, c_prev, a_hidden, a2_w, a2_b, residual, ssg_out, h_out, c_out);
}

// Round 15
// 217.890 us; speedup vs baseline: 2.4815x; 2.4815x over previous
//
#include <hip/hip_runtime.h>
#include <hip/hip_bf16.h>

// Problem constants
#define B_DIM 4096
#define H_DIM 1024
#define K1    2048   // IN + H
#define N1    6144   // 5 gates * 1024 + a1 (1024)

typedef __attribute__((ext_vector_type(8))) short bf16x8;
typedef __attribute__((ext_vector_type(4))) float f32x4;

__device__ __forceinline__ unsigned short f2bf(float f) {
  unsigned int x = __float_as_uint(f);
  x += 0x7fffu + ((x >> 16) & 1u);   // RTNE
  return (unsigned short)(x >> 16);
}
__device__ __forceinline__ float bf2f(unsigned short u) {
  return __uint_as_float(((unsigned int)u) << 16);
}
__device__ __forceinline__ float fast_sigmoid(float x) {
  return __builtin_amdgcn_rcpf(1.0f + __expf(-x));
}
__device__ __forceinline__ float fast_tanh(float x) {
  return 1.0f - 2.0f * __builtin_amdgcn_rcpf(1.0f + __expf(2.0f * x));
}
__device__ __forceinline__ void gload_lds16(const void* g, void* l) {
  __builtin_amdgcn_global_load_lds(
      (const __attribute__((address_space(1))) void*)g,
      (__attribute__((address_space(3))) void*)l, 16, 0, 0);
}

// m201's st_16x32 swizzle: XOR byte-bit5 with bit9 within a 1024B subtile.
__device__ __forceinline__ int swz1k(int x) {
  return x ^ (((x >> 9) & 1) << 5);
}

// ---------------------------------------------------------------------------
// prep: build bf16 activations + weight panels in workspace (grid-stride vec4)
// ---------------------------------------------------------------------------
__global__ __launch_bounds__(256) void prep_kernel(
    const float* __restrict__ x, const float* __restrict__ h,
    const float* __restrict__ ssg_state,
    const float* __restrict__ Wx, const float* __restrict__ Ux,
    const float* __restrict__ a1_w,
    const float* __restrict__ ssg_w, const float* __restrict__ r1_w,
    const float* __restrict__ r2_w, const float* __restrict__ r3_w,
    unsigned short* __restrict__ combined,
    unsigned short* __restrict__ ssg_in,
    unsigned short* __restrict__ W1,
    unsigned short* __restrict__ W2,
    unsigned short* __restrict__ W3,
    unsigned short* __restrict__ W4)
{
  const size_t NV0 = (size_t)B_DIM * K1 / 4;      // combined
  const size_t NV1 = (size_t)B_DIM * H_DIM / 4;   // ssg_in
  const size_t NV3 = (size_t)N1 * K1 / 4;         // W1
  const size_t NV4 = (size_t)2048 * H_DIM / 4;    // W2
  const size_t NV5 = (size_t)H_DIM * H_DIM / 4;   // W3, W4
  const size_t total = NV0 + NV1 + NV3 + NV4 + NV5 + NV5;
  const size_t stride = (size_t)gridDim.x * blockDim.x;

  for (size_t v = (size_t)blockIdx.x * blockDim.x + threadIdx.x; v < total; v += stride) {
    size_t idx = v;
    const float* src;
    unsigned short* dst;
    if (idx < NV0) {
      size_t e = idx * 4, b = e >> 11, k = e & 2047;
      src = (k < 1024) ? &x[(b << 10) + k] : &h[(b << 10) + (k - 1024)];
      dst = &combined[e];
    } else if ((idx -= NV0) < NV1) {
      size_t e = idx * 4;
      float4 a = *(const float4*)&ssg_state[e];
      float4 c = *(const float4*)&h[e];
      ushort4 o;
      o.x = f2bf(a.x + c.x); o.y = f2bf(a.y + c.y);
      o.z = f2bf(a.z + c.z); o.w = f2bf(a.w + c.w);
      *(ushort4*)&ssg_in[e] = o;
      continue;
    } else if ((idx -= NV1) < NV3) {
      size_t e = idx * 4, n = e >> 11, k = e & 2047;
      if (n < 5120) src = (k < 1024) ? &Wx[(n << 10) + k] : &Ux[(n << 10) + (k - 1024)];
      else          src = &a1_w[((n - 5120) << 11) + k];
      dst = &W1[e];
    } else if ((idx -= NV3) < NV4) {
      size_t e = idx * 4, n = e >> 10, k = e & 1023;
      src = (n < 1024) ? &ssg_w[(n << 10) + k] : &r1_w[((n - 1024) << 10) + k];
      dst = &W2[e];
    } else if ((idx -= NV4) < NV5) {
      size_t e = idx * 4; src = &r2_w[e]; dst = &W3[e];
    } else {
      idx -= NV5;
      size_t e = idx * 4; src = &r3_w[e]; dst = &W4[e];
    }
    float4 a = *(const float4*)src;
    ushort4 o;
    o.x = f2bf(a.x); o.y = f2bf(a.y); o.z = f2bf(a.z); o.w = f2bf(a.w);
    *(ushort4*)dst = o;
  }
}

// ---------------------------------------------------------------------------
// body192: 128x192 tile, 4 waves 2x2 (per-wave 64x96, 4x6 frags), 1-barrier
// K-tile schedule, 80 KB LDS (2 blocks/CU). R12-verified best.
// ---------------------------------------------------------------------------
__device__ __forceinline__ void body192(
    unsigned short* lds, const int bid,
    const unsigned short* __restrict__ A,
    const unsigned short* __restrict__ W,
    const float* __restrict__ bWx, const float* __restrict__ bUx,
    const float* __restrict__ a1_b,
    unsigned short* __restrict__ gates,
    unsigned short* __restrict__ a_hidden)
{
  constexpr int NT  = 32;       // K = 2048
  constexpr int NTN = 32;       // 6144 / 192
  constexpr int NWG = 32 * NTN; // 1024

  const int tid  = threadIdx.x;
  const int wave = tid >> 6;
  const int lane = tid & 63;
  const int wm = wave >> 1;     // row half (64)
  const int wn = wave & 1;      // col half (96)

  const int swz = (bid & 7) * (NWG / 8) + (bid >> 3);
  const int tm = swz / NTN, tn = swz % NTN;
  const int tmB = tm * 128, tnB = tn * 192;

  const int sidx = swz1k(lane * 16);
  const int r_l  = sidx >> 6;
  const int kel  = (sidx & 63) >> 1;
  const unsigned short* pA[2][2];
  const unsigned short* pB[3][2];
#pragma unroll
  for (int rg = 0; rg < 2; ++rg)
#pragma unroll
    for (int j = 0; j < 2; ++j)
      pA[rg][j] = A + (size_t)(tmB + (wave * 2 + rg) * 16 + r_l) * K1 + j * 32 + kel;
#pragma unroll
  for (int rg = 0; rg < 3; ++rg)
#pragma unroll
    for (int j = 0; j < 2; ++j)
      pB[rg][j] = W + (size_t)(tnB + (wave * 3 + rg) * 16 + r_l) * K1 + j * 32 + kel;

#define STAGE_A(tt) do { const int p_ = (tt) & 1;                                \
    _Pragma("unroll")                                                            \
    for (int rg = 0; rg < 2; ++rg)                                               \
      _Pragma("unroll")                                                          \
      for (int j = 0; j < 2; ++j)                                                \
        gload_lds16(pA[rg][j] + (size_t)(tt) * 64,                               \
                    &lds[p_ * 20480 + ((wave * 2 + rg) * 2 + j) * 512]);         \
  } while (0)
#define STAGE_B(tt) do { const int p_ = (tt) & 1;                                \
    _Pragma("unroll")                                                            \
    for (int rg = 0; rg < 3; ++rg)                                               \
      _Pragma("unroll")                                                          \
      for (int j = 0; j < 2; ++j)                                                \
        gload_lds16(pB[rg][j] + (size_t)(tt) * 64,                               \
                    &lds[p_ * 20480 + 8192 + ((wave * 3 + rg) * 2 + j) * 512]);  \
  } while (0)

  const int loc = swz1k((lane & 15) * 64 + (lane >> 4) * 16);

  f32x4 acc[4][6];
#pragma unroll
  for (int m = 0; m < 4; ++m)
#pragma unroll
    for (int n = 0; n < 6; ++n) acc[m][n] = (f32x4){0.f, 0.f, 0.f, 0.f};

  STAGE_A(0); STAGE_B(0);   // 10 vmem ops

#define MFMA24(aV, bV) do {                                                      \
    _Pragma("unroll")                                                            \
    for (int n = 0; n < 6; ++n) {                                                \
      _Pragma("unroll")                                                          \
      for (int m = 0; m < 4; ++m)                                                \
        acc[m][n] = __builtin_amdgcn_mfma_f32_16x16x32_bf16(                     \
            aV[m], bV[n], acc[m][n], 0, 0, 0);                                   \
    } } while (0)

  const char* lchar = (const char*)lds;
  for (int t = 0; t < NT; ++t) {
    asm volatile("s_waitcnt vmcnt(0)" ::: "memory");
    __builtin_amdgcn_s_barrier();

    const char* base = lchar + (t & 1) * 40960;
    const char* bA = base + wm * 8192 + loc;
    const char* bB = base + 16384 + wn * 12288 + loc;

    bf16x8 a0[4], a1[4], b0[6], b1[6];
#pragma unroll
    for (int n = 0; n < 6; ++n) b0[n] = *(const bf16x8*)(bB + (2 * n + 0) * 1024);
#pragma unroll
    for (int m = 0; m < 4; ++m) a0[m] = *(const bf16x8*)(bA + (2 * m + 0) * 1024);
    if (t + 1 < NT) STAGE_A(t + 1);
#pragma unroll
    for (int n = 0; n < 6; ++n) b1[n] = *(const bf16x8*)(bB + (2 * n + 1) * 1024);
#pragma unroll
    for (int m = 0; m < 4; ++m) a1[m] = *(const bf16x8*)(bA + (2 * m + 1) * 1024);
    if (t + 1 < NT) STAGE_B(t + 1);

    __builtin_amdgcn_s_setprio(1);
    MFMA24(a0, b0);
    __builtin_amdgcn_s_setprio(0);
    __builtin_amdgcn_s_setprio(1);
    MFMA24(a1, b1);
    __builtin_amdgcn_s_setprio(0);
  }
#undef MFMA24
#undef STAGE_A
#undef STAGE_B

  unsigned short* slab = &lds[wave * 1536];
  const int l15 = lane & 15, lq4 = (lane >> 4) << 2;
  const int colg0 = tnB + wn * 96;
  const int rowg0 = tmB + wm * 64;
  const size_t BH = (size_t)B_DIM * H_DIM;

  float biasv[6];
  int amode[6];   // 0 sigmoid, 1 tanh, 2 relu
#pragma unroll
  for (int fn = 0; fn < 6; ++fn) {
    const int c = colg0 + fn * 16 + l15;
    if (c < 5120) {
      biasv[fn] = bWx[c] + bUx[c];
      amode[fn] = ((c >> 10) == 3) ? 1 : 0;
    } else {
      biasv[fn] = a1_b[c - 5120];
      amode[fn] = 2;
    }
  }
  __builtin_amdgcn_s_barrier();
#pragma unroll
  for (int fm = 0; fm < 4; ++fm) {
#pragma unroll
    for (int fn = 0; fn < 6; ++fn) {
      f32x4 v = acc[fm][fn];
#pragma unroll
      for (int j = 0; j < 4; ++j) {
        const int row = lq4 + j;
        const float xv = v[j] + biasv[fn];
        const float res = (amode[fn] == 1) ? fast_tanh(xv)
                         : (amode[fn] == 0) ? fast_sigmoid(xv)
                         : fmaxf(xv, 0.f);
        const int byte = (row * 192 + (fn * 16 + l15) * 2) ^ (((row >> 2) & 1) << 5);
        slab[byte >> 1] = f2bf(res);
      }
    }
    asm volatile("s_waitcnt lgkmcnt(0)" ::: "memory");
    __builtin_amdgcn_sched_barrier(0);
#pragma unroll
    for (int p = 0; p < 3; ++p) {
      const int id = p * 64 + lane;
      const int row = id / 12, cc = id - row * 12;
      const int byte = (row * 192 + cc * 16) ^ (((row >> 2) & 1) << 5);
      bf16x8 pk = *(const bf16x8*)((const char*)slab + byte);
      const int col = colg0 + cc * 8;
      const size_t r = (size_t)(rowg0 + fm * 16 + row);
      unsigned short* dst;
      if (col < 5120) dst = gates + (size_t)(col >> 10) * BH + r * 1024 + (col & 1023);
      else            dst = a_hidden + r * 1024 + (col - 5120);
      *(bf16x8*)dst = pk;
    }
    asm volatile("s_waitcnt lgkmcnt(0)" ::: "memory");
    __builtin_amdgcn_sched_barrier(0);
  }
}

// ---------------------------------------------------------------------------
// gemm_body<NT, MODE=1>: 128x128 structure for ssg+r1 (R11-verified).
// ---------------------------------------------------------------------------
template <int NT, int MODE>
__device__ __forceinline__ void gemm_body(
    unsigned short* lds, const int bid,
    const unsigned short* __restrict__ A0,
    const unsigned short* __restrict__ A1,
    const unsigned short* __restrict__ W,
    const float* __restrict__ b0, const float* __restrict__ b1,
    void* __restrict__ out0, void* __restrict__ out1)
{
  constexpr int KDIM = NT * 64;
  constexpr int NTN  = 16;
  constexpr int NWG  = 32 * NTN;

  const int tid  = threadIdx.x;
  const int wave = tid >> 6;
  const int lane = tid & 63;
  const int wm = wave >> 1;
  const int wn = wave & 1;

  const int swz = (bid & 7) * (NWG / 8) + (bid >> 3);
  const int tm = swz / NTN, tn = swz % NTN;
  const int tmB = tm * 128, tnB = tn * 128;

  const unsigned short* Abase = A0;
  int lda = 1024;
  if (tn >= 8) { Abase = A1; lda = 2048; }

  const int sidx = swz1k(lane * 16);
  const int r_l  = sidx >> 6;
  const int kel  = (sidx & 63) >> 1;
  const unsigned short* pA[2][2];
  const unsigned short* pB[2][2];
#pragma unroll
  for (int rg = 0; rg < 2; ++rg)
#pragma unroll
    for (int j = 0; j < 2; ++j) {
      const int rr = wave * 32 + rg * 16 + r_l;
      const int kk0 = j * 32 + kel;
      pA[rg][j] = Abase + (size_t)(tmB + rr) * lda + kk0;
      pB[rg][j] = W + (size_t)(tnB + rr) * KDIM + kk0;
    }

#define STAGE_A(tt) do { const int p_ = (tt) & 1;                                \
    _Pragma("unroll")                                                            \
    for (int rg = 0; rg < 2; ++rg)                                               \
      _Pragma("unroll")                                                          \
      for (int j = 0; j < 2; ++j)                                                \
        gload_lds16(pA[rg][j] + (size_t)(tt) * 64,                               \
                    &lds[p_ * 16384 + ((wave * 2 + rg) * 2 + j) * 512]);         \
  } while (0)
#define STAGE_B(tt) do { const int p_ = (tt) & 1;                                \
    _Pragma("unroll")                                                            \
    for (int rg = 0; rg < 2; ++rg)                                               \
      _Pragma("unroll")                                                          \
      for (int j = 0; j < 2; ++j)                                                \
        gload_lds16(pB[rg][j] + (size_t)(tt) * 64,                               \
                    &lds[p_ * 16384 + 8192 + ((wave * 2 + rg) * 2 + j) * 512]);  \
  } while (0)

  const int loc = swz1k((lane & 15) * 64 + (lane >> 4) * 16);

  f32x4 acc[4][4];
#pragma unroll
  for (int m = 0; m < 4; ++m)
#pragma unroll
    for (int n = 0; n < 4; ++n) acc[m][n] = (f32x4){0.f, 0.f, 0.f, 0.f};

  STAGE_A(0); STAGE_B(0);

#define MFMA16(aV, bV) do {                                                      \
    _Pragma("unroll")                                                            \
    for (int n = 0; n < 4; ++n) {                                                \
      _Pragma("unroll")                                                          \
      for (int m = 0; m < 4; ++m)                                                \
        acc[m][n] = __builtin_amdgcn_mfma_f32_16x16x32_bf16(                     \
            aV[m], bV[n], acc[m][n], 0, 0, 0);                                   \
    } } while (0)

  const char* lchar = (const char*)lds;
  for (int t = 0; t < NT; ++t) {
    asm volatile("s_waitcnt vmcnt(0)" ::: "memory");
    __builtin_amdgcn_s_barrier();

    const char* base = lchar + (t & 1) * 32768;
    const char* bA = base + wm * 8192 + loc;
    const char* bB = base + 16384 + wn * 8192 + loc;

    bf16x8 a0[4], a1[4], b0v[4], b1v[4];
#pragma unroll
    for (int n = 0; n < 4; ++n) b0v[n] = *(const bf16x8*)(bB + (2 * n + 0) * 1024);
#pragma unroll
    for (int m = 0; m < 4; ++m) a0[m] = *(const bf16x8*)(bA + (2 * m + 0) * 1024);
    if (t + 1 < NT) STAGE_A(t + 1);
#pragma unroll
    for (int n = 0; n < 4; ++n) b1v[n] = *(const bf16x8*)(bB + (2 * n + 1) * 1024);
#pragma unroll
    for (int m = 0; m < 4; ++m) a1[m] = *(const bf16x8*)(bA + (2 * m + 1) * 1024);
    if (t + 1 < NT) STAGE_B(t + 1);

    __builtin_amdgcn_s_setprio(1);
    MFMA16(a0, b0v);
    __builtin_amdgcn_s_setprio(0);
    __builtin_amdgcn_s_setprio(1);
    MFMA16(a1, b1v);
    __builtin_amdgcn_s_setprio(0);
  }
#undef MFMA16
#undef STAGE_A
#undef STAGE_B

  const int l15 = lane & 15, lq4 = (lane >> 4) << 2;
  const int rowg0 = tmB + wm * 64;

  if (tn < 8) {
    const int col0 = tn * 128 + wn * 64;
#pragma unroll
    for (int fn = 0; fn < 4; ++fn) {
      const int col = col0 + fn * 16 + l15;
      const float bias = b0[col];
#pragma unroll
      for (int fm = 0; fm < 4; ++fm) {
        f32x4 v = acc[fm][fn];
#pragma unroll
        for (int j = 0; j < 4; ++j) {
          const int r = rowg0 + fm * 16 + lq4 + j;
          ((float*)out0)[(size_t)r * 1024 + col] = v[j] + bias;
        }
      }
    }
    return;
  }

  unsigned short* slab = &lds[wave * 1024];
  const int lr8 = lane >> 3, lc8 = lane & 7;
  const int colg0 = (tn - 8) * 128 + wn * 64;
  unsigned short* outbase = (unsigned short*)out1;
  float biasv[4];
#pragma unroll
  for (int fn = 0; fn < 4; ++fn) biasv[fn] = b1[colg0 + fn * 16 + l15];
  __builtin_amdgcn_s_barrier();
#pragma unroll
  for (int fm = 0; fm < 4; ++fm) {
#pragma unroll
    for (int fn = 0; fn < 4; ++fn) {
      f32x4 v = acc[fm][fn];
#pragma unroll
      for (int j = 0; j < 4; ++j) {
        const int row = lq4 + j;
        const float res = fmaxf(v[j] + biasv[fn], 0.f);
        const int colb = ((fn * 16 + l15) * 2) ^ (((row >> 2) & 3) << 5);
        slab[(row * 128 + colb) >> 1] = f2bf(res);
      }
    }
    asm volatile("s_waitcnt lgkmcnt(0)" ::: "memory");
    __builtin_amdgcn_sched_barrier(0);
#pragma unroll
    for (int rd = 0; rd < 2; ++rd) {
      const int row = rd * 8 + lr8;
      const int cb = (lc8 * 16) ^ (((row >> 2) & 3) << 5);
      bf16x8 pk = *(const bf16x8*)((const char*)slab + row * 128 + cb);
      const size_t r = (size_t)(rowg0 + fm * 16 + row);
      *(bf16x8*)&outbase[r * 1024 + colg0 + lc8 * 8] = pk;
    }
    asm volatile("s_waitcnt lgkmcnt(0)" ::: "memory");
    __builtin_amdgcn_sched_barrier(0);
  }
}

// ---------------------------------------------------------------------------
// merged big GEMM: blocks [0,1024) = gates+a_hidden (128x192); [1024,1536) =
// ssg+r1 (128x128). 80 KB shared -> 2 blocks/CU.
// ---------------------------------------------------------------------------
__global__ __launch_bounds__(256, 2) void gemm_big(
    const unsigned short* __restrict__ combined,
    const unsigned short* __restrict__ ssg_in,
    const unsigned short* __restrict__ W1,
    const unsigned short* __restrict__ W2,
    const float* __restrict__ bWx, const float* __restrict__ bUx,
    const float* __restrict__ a1_b,
    const float* __restrict__ ssg_b, const float* __restrict__ r1_b,
    unsigned short* __restrict__ gates,
    unsigned short* __restrict__ a_hidden,
    float* __restrict__ ssg_out,
    unsigned short* __restrict__ r1)
{
  __shared__ unsigned short lds[40960];  // 80 KiB
  const int bid = blockIdx.x;
  if (bid < 1024) {
    body192(lds, bid, combined, W1, bWx, bUx, a1_b, gates, a_hidden);
  } else {
    gemm_body<16, 1>(lds, bid - 1024, ssg_in, combined + 1024, W2,
                     ssg_b, r1_b, ssg_out, r1);
  }
}

// ---------------------------------------------------------------------------
// gemm_small64<MODE>: 64x128 tile, BK=64, 48 KB LDS, 3 blocks/CU, grid 512.
// MODE 2: relu -> bf16 out.  MODE 3: fp32 + bias out.
// ---------------------------------------------------------------------------
template <int MODE>
__global__ __launch_bounds__(256, 3) void gemm_small64(
    const unsigned short* __restrict__ A,
    const unsigned short* __restrict__ W,
    const float* __restrict__ bias,
    void* __restrict__ out)
{
  __shared__ unsigned short lds[24576];  // 48 KiB
  constexpr int NT = 16;                 // K = 1024

  const int tid  = threadIdx.x;
  const int wave = tid >> 6;
  const int lane = tid & 63;
  const int wm = wave >> 1;   // row half (32)
  const int wn = wave & 1;    // col half (64)

  const int bid = blockIdx.x;
  const int swz = (bid & 7) * 64 + (bid >> 3);   // NWG = 512, bijective
  const int tm = swz >> 3, tn = swz & 7;
  const int tmB = tm * 64, tnB = tn * 128;

  const int sidx = swz1k(lane * 16);
  const int r_l  = sidx >> 6;
  const int kel  = (sidx & 63) >> 1;
  const unsigned short* pA[2];
  const unsigned short* pB[2][2];
#pragma unroll
  for (int j = 0; j < 2; ++j)
    pA[j] = A + (size_t)(tmB + wave * 16 + r_l) * 1024 + j * 32 + kel;
#pragma unroll
  for (int rg = 0; rg < 2; ++rg)
#pragma unroll
    for (int j = 0; j < 2; ++j)
      pB[rg][j] = W + (size_t)(tnB + (wave * 2 + rg) * 16 + r_l) * 1024 + j * 32 + kel;

#define STAGE_A(tt) do { const int p_ = (tt) & 1;                                \
    _Pragma("unroll")                                                            \
    for (int j = 0; j < 2; ++j)                                                  \
      gload_lds16(pA[j] + (size_t)(tt) * 64,                                     \
                  &lds[p_ * 12288 + (wave * 2 + j) * 512]);                      \
  } while (0)
#define STAGE_B(tt) do { const int p_ = (tt) & 1;                                \
    _Pragma("unroll")                                                            \
    for (int rg = 0; rg < 2; ++rg)                                               \
      _Pragma("unroll")                                                          \
      for (int j = 0; j < 2; ++j)                                                \
        gload_lds16(pB[rg][j] + (size_t)(tt) * 64,                               \
                    &lds[p_ * 12288 + 4096 + ((wave * 2 + rg) * 2 + j) * 512]);  \
  } while (0)

  const int loc = swz1k((lane & 15) * 64 + (lane >> 4) * 16);

  f32x4 acc[2][4];
#pragma unroll
  for (int m = 0; m < 2; ++m)
#pragma unroll
    for (int n = 0; n < 4; ++n) acc[m][n] = (f32x4){0.f, 0.f, 0.f, 0.f};

  STAGE_A(0); STAGE_B(0);   // 6 vmem ops

  const char* lchar = (const char*)lds;
  for (int t = 0; t < NT; ++t) {
    asm volatile("s_waitcnt vmcnt(0)" ::: "memory");
    __builtin_amdgcn_s_barrier();

    const char* base = lchar + (t & 1) * 24576;
    const char* bA = base + wm * 4096 + loc;
    const char* bB = base + 8192 + wn * 8192 + loc;

    bf16x8 a0[2], a1[2], b0[4], b1[4];
#pragma unroll
    for (int n = 0; n < 4; ++n) b0[n] = *(const bf16x8*)(bB + (2 * n + 0) * 1024);
#pragma unroll
    for (int m = 0; m < 2; ++m) a0[m] = *(const bf16x8*)(bA + (2 * m + 0) * 1024);
    if (t + 1 < NT) STAGE_A(t + 1);
#pragma unroll
    for (int n = 0; n < 4; ++n) b1[n] = *(const bf16x8*)(bB + (2 * n + 1) * 1024);
#pragma unroll
    for (int m = 0; m < 2; ++m) a1[m] = *(const bf16x8*)(bA + (2 * m + 1) * 1024);
    if (t + 1 < NT) STAGE_B(t + 1);

    __builtin_amdgcn_s_setprio(1);
#pragma unroll
    for (int n = 0; n < 4; ++n)
#pragma unroll
      for (int m = 0; m < 2; ++m)
        acc[m][n] = __builtin_amdgcn_mfma_f32_16x16x32_bf16(a0[m], b0[n], acc[m][n], 0, 0, 0);
    __builtin_amdgcn_s_setprio(0);
    __builtin_amdgcn_s_setprio(1);
#pragma unroll
    for (int n = 0; n < 4; ++n)
#pragma unroll
      for (int m = 0; m < 2; ++m)
        acc[m][n] = __builtin_amdgcn_mfma_f32_16x16x32_bf16(a1[m], b1[n], acc[m][n], 0, 0, 0);
    __builtin_amdgcn_s_setprio(0);
  }
#undef STAGE_A
#undef STAGE_B

  const int l15 = lane & 15, lq4 = (lane >> 4) << 2;
  const int rowg0 = tmB + wm * 32;

  if (MODE == 3) {
    const int col0 = tnB + wn * 64;
#pragma unroll
    for (int fn = 0; fn < 4; ++fn) {
      const int col = col0 + fn * 16 + l15;
      const float bv = bias[col];
#pragma unroll
      for (int fm = 0; fm < 2; ++fm) {
        f32x4 v = acc[fm][fn];
#pragma unroll
        for (int j = 0; j < 4; ++j) {
          const int r = rowg0 + fm * 16 + lq4 + j;
          ((float*)out)[(size_t)r * 1024 + col] = v[j] + bv;
        }
      }
    }
    return;
  }

  unsigned short* slab = &lds[wave * 1024];
  const int lr8 = lane >> 3, lc8 = lane & 7;
  const int colg0 = tnB + wn * 64;
  unsigned short* outbase = (unsigned short*)out;
  float biasv[4];
#pragma unroll
  for (int fn = 0; fn < 4; ++fn) biasv[fn] = bias[colg0 + fn * 16 + l15];
  __builtin_amdgcn_s_barrier();
#pragma unroll
  for (int fm = 0; fm < 2; ++fm) {
#pragma unroll
    for (int fn = 0; fn < 4; ++fn) {
      f32x4 v = acc[fm][fn];
#pragma unroll
      for (int j = 0; j < 4; ++j) {
        const int row = lq4 + j;
        const float res = fmaxf(v[j] + biasv[fn], 0.f);
        const int colb = ((fn * 16 + l15) * 2) ^ (((row >> 2) & 3) << 5);
        slab[(row * 128 + colb) >> 1] = f2bf(res);
      }
    }
    asm volatile("s_waitcnt lgkmcnt(0)" ::: "memory");
    __builtin_amdgcn_sched_barrier(0);
#pragma unroll
    for (int rd = 0; rd < 2; ++rd) {
      const int row = rd * 8 + lr8;
      const int cb = (lc8 * 16) ^ (((row >> 2) & 3) << 5);
      bf16x8 pk = *(const bf16x8*)((const char*)slab + row * 128 + cb);
      const size_t r = (size_t)(rowg0 + fm * 16 + row);
      *(bf16x8*)&outbase[r * 1024 + colg0 + lc8 * 8] = pk;
    }
    asm volatile("s_waitcnt lgkmcnt(0)" ::: "memory");
    __builtin_amdgcn_sched_barrier(0);
  }
}

// ---------------------------------------------------------------------------
// final fused: per-row alpha (4-wave reduce) + vec4 elementwise cell update.
// ---------------------------------------------------------------------------
__global__ __launch_bounds__(256) void final_fused(
    const unsigned short* __restrict__ gates,
    const float* __restrict__ c_prev,
    const unsigned short* __restrict__ a_hidden,
    const float* __restrict__ a2_w, const float* __restrict__ a2_b,
    const float* __restrict__ residual,
    const float* __restrict__ ssg_new,
    float* __restrict__ h_out, float* __restrict__ c_out)
{
  __shared__ float red[5];
  const int r = blockIdx.x;
  const int tid = threadIdx.x;
  const size_t BH = (size_t)B_DIM * H_DIM;

  {
    ushort4 u = *(const ushort4*)&a_hidden[(size_t)r * 1024 + tid * 4];
    float4 w = *(const float4*)&a2_w[tid * 4];
    float s = bf2f(u.x) * w.x + bf2f(u.y) * w.y + bf2f(u.z) * w.z + bf2f(u.w) * w.w;
#pragma unroll
    for (int off = 32; off; off >>= 1) s += __shfl_xor(s, off);
    if ((tid & 63) == 0) red[tid >> 6] = s;
  }
  __syncthreads();
  if (tid == 0)
    red[4] = fast_sigmoid(red[0] + red[1] + red[2] + red[3] + a2_b[0]);
  __syncthreads();
  const float al = red[4];

  const size_t e = (size_t)r * 1024 + tid * 4;
  ushort4 iu = *(const ushort4*)&gates[e];
  ushort4 fu = *(const ushort4*)&gates[BH + e];
  ushort4 ou = *(const ushort4*)&gates[2 * BH + e];
  ushort4 cu = *(const ushort4*)&gates[3 * BH + e];
  ushort4 su = *(const ushort4*)&gates[4 * BH + e];
  float4 cp = *(const float4*)&c_prev[e];
  float4 rs = *(const float4*)&residual[e];
  float4 sg = *(const float4*)&ssg_new[e];
  float4 ho, co;
  co.x = bf2f(fu.x) * cp.x + bf2f(iu.x) * bf2f(cu.x) * bf2f(su.x) * al * sg.x + rs.x;
  co.y = bf2f(fu.y) * cp.y + bf2f(iu.y) * bf2f(cu.y) * bf2f(su.y) * al * sg.y + rs.y;
  co.z = bf2f(fu.z) * cp.z + bf2f(iu.z) * bf2f(cu.z) * bf2f(su.z) * al * sg.z + rs.z;
  co.w = bf2f(fu.w) * cp.w + bf2f(iu.w) * bf2f(cu.w) * bf2f(su.w) * al * sg.w + rs.w;
  ho.x = bf2f(ou.x) * fast_tanh(co.x);
  ho.y = bf2f(ou.y) * fast_tanh(co.y);
  ho.z = bf2f(ou.z) * fast_tanh(co.z);
  ho.w = bf2f(ou.w) * fast_tanh(co.w);
  *(float4*)&h_out[e] = ho;
  *(float4*)&c_out[e] = co;
}

// ---------------------------------------------------------------------------
extern "C" void kernel_launch(void* const* d_in, const int* in_sizes, int n_in,
                              void* d_out, int out_size, void* d_ws, size_t ws_size,
                              hipStream_t stream)
{
  (void)in_sizes; (void)n_in; (void)out_size; (void)ws_size;
  const float* x         = (const float*)d_in[0];
  const float* h_prev    = (const float*)d_in[1];
  const float* c_prev    = (const float*)d_in[2];
  const float* ssg_state = (const float*)d_in[3];
  const float* Wx        = (const float*)d_in[4];
  const float* bWx       = (const float*)d_in[5];
  const float* Ux        = (const float*)d_in[6];
  const float* bUx       = (const float*)d_in[7];
  const float* a1_w      = (const float*)d_in[8];
  const float* a1_b      = (const float*)d_in[9];
  const float* a2_w      = (const float*)d_in[10];
  const float* a2_b      = (const float*)d_in[11];
  const float* r1_w      = (const float*)d_in[12];
  const float* r1_b      = (const float*)d_in[13];
  const float* r2_w      = (const float*)d_in[14];
  const float* r2_b      = (const float*)d_in[15];
  const float* r3_w      = (const float*)d_in[16];
  const float* r3_b      = (const float*)d_in[17];
  const float* ssg_w     = (const float*)d_in[18];
  const float* ssg_b     = (const float*)d_in[19];

  char* ws = (char*)d_ws;
  unsigned short* combined = (unsigned short*)(ws);               // 16,777,216
  unsigned short* ssg_in   = (unsigned short*)(ws + 16777216);    //  8,388,608
  unsigned short* W1       = (unsigned short*)(ws + 33554432);    // 25,165,824
  unsigned short* W2       = (unsigned short*)(ws + 58720256);    //  4,194,304
  unsigned short* W3       = (unsigned short*)(ws + 62914560);    //  2,097,152
  unsigned short* W4       = (unsigned short*)(ws + 65011712);    //  2,097,152
  unsigned short* gates    = (unsigned short*)(ws + 67108864);    // 41,943,040
  unsigned short* a_hidden = (unsigned short*)(ws + 109051904);   //  8,388,608
  unsigned short* r1       = (unsigned short*)(ws + 117456896);   //  8,388,608
  unsigned short* r2       = (unsigned short*)(ws + 125845504);   //  8,388,608
  float*          residual = (float*)(ws + 134234112);            // 16,777,216

  float* h_out   = (float*)d_out;
  float* c_out   = h_out + (size_t)B_DIM * H_DIM;
  float* ssg_out = c_out + (size_t)B_DIM * H_DIM;

  prep_kernel<<<4096, 256, 0, stream>>>(x, h_prev, ssg_state, Wx, Ux, a1_w,
                                        ssg_w, r1_w, r2_w, r3_w,
                                        combined, ssg_in, W1, W2, W3, W4);

  gemm_big<<<1536, 256, 0, stream>>>(
      combined, ssg_in, W1, W2, bWx, bUx, a1_b, ssg_b, r1_b,
      gates, a_hidden, ssg_out, r1);

  gemm_small64<2><<<512, 256, 0, stream>>>(r1, W3, r2_b, r2);

  gemm_small64<3><<<512, 256, 0, stream>>>(r2, W4, r3_b, residual);

  final_fused<<<B_DIM, 256, 0, stream>>>(
      gates, c_prev, a_hidden, a2_w, a2_b, residual, ssg_out, h_out, c_out);
}

// Round 16
// 216.654 us; speedup vs baseline: 2.4956x; 1.0057x over previous
//
#include <hip/hip_runtime.h>
#include <hip/hip_bf16.h>

// Problem constants
#define B_DIM 4096
#define H_DIM 1024
#define K1    2048   // IN + H
#define N1    6144   // 5 gates * 1024 + a1 (1024)

typedef __attribute__((ext_vector_type(8))) short bf16x8;
typedef __attribute__((ext_vector_type(4))) float f32x4;

__device__ __forceinline__ unsigned short f2bf(float f) {
  unsigned int x = __float_as_uint(f);
  x += 0x7fffu + ((x >> 16) & 1u);   // RTNE
  return (unsigned short)(x >> 16);
}
__device__ __forceinline__ float bf2f(unsigned short u) {
  return __uint_as_float(((unsigned int)u) << 16);
}
__device__ __forceinline__ float fast_sigmoid(float x) {
  return __builtin_amdgcn_rcpf(1.0f + __expf(-x));
}
__device__ __forceinline__ float fast_tanh(float x) {
  return 1.0f - 2.0f * __builtin_amdgcn_rcpf(1.0f + __expf(2.0f * x));
}
__device__ __forceinline__ void gload_lds16(const void* g, void* l) {
  __builtin_amdgcn_global_load_lds(
      (const __attribute__((address_space(1))) void*)g,
      (__attribute__((address_space(3))) void*)l, 16, 0, 0);
}

// m201's st_16x32 swizzle: XOR byte-bit5 with bit9 within a 1024B subtile.
__device__ __forceinline__ int swz1k(int x) {
  return x ^ (((x >> 9) & 1) << 5);
}

// ---------------------------------------------------------------------------
// prep: build bf16 activations + weight panels in workspace (grid-stride vec4)
// ---------------------------------------------------------------------------
__global__ __launch_bounds__(256) void prep_kernel(
    const float* __restrict__ x, const float* __restrict__ h,
    const float* __restrict__ ssg_state,
    const float* __restrict__ Wx, const float* __restrict__ Ux,
    const float* __restrict__ a1_w,
    const float* __restrict__ ssg_w, const float* __restrict__ r1_w,
    const float* __restrict__ r2_w, const float* __restrict__ r3_w,
    unsigned short* __restrict__ combined,
    unsigned short* __restrict__ ssg_in,
    unsigned short* __restrict__ W1,
    unsigned short* __restrict__ W2,
    unsigned short* __restrict__ W3,
    unsigned short* __restrict__ W4)
{
  const size_t NV0 = (size_t)B_DIM * K1 / 4;      // combined
  const size_t NV1 = (size_t)B_DIM * H_DIM / 4;   // ssg_in
  const size_t NV3 = (size_t)N1 * K1 / 4;         // W1
  const size_t NV4 = (size_t)2048 * H_DIM / 4;    // W2
  const size_t NV5 = (size_t)H_DIM * H_DIM / 4;   // W3, W4
  const size_t total = NV0 + NV1 + NV3 + NV4 + NV5 + NV5;
  const size_t stride = (size_t)gridDim.x * blockDim.x;

  for (size_t v = (size_t)blockIdx.x * blockDim.x + threadIdx.x; v < total; v += stride) {
    size_t idx = v;
    const float* src;
    unsigned short* dst;
    if (idx < NV0) {
      size_t e = idx * 4, b = e >> 11, k = e & 2047;
      src = (k < 1024) ? &x[(b << 10) + k] : &h[(b << 10) + (k - 1024)];
      dst = &combined[e];
    } else if ((idx -= NV0) < NV1) {
      size_t e = idx * 4;
      float4 a = *(const float4*)&ssg_state[e];
      float4 c = *(const float4*)&h[e];
      ushort4 o;
      o.x = f2bf(a.x + c.x); o.y = f2bf(a.y + c.y);
      o.z = f2bf(a.z + c.z); o.w = f2bf(a.w + c.w);
      *(ushort4*)&ssg_in[e] = o;
      continue;
    } else if ((idx -= NV1) < NV3) {
      size_t e = idx * 4, n = e >> 11, k = e & 2047;
      if (n < 5120) src = (k < 1024) ? &Wx[(n << 10) + k] : &Ux[(n << 10) + (k - 1024)];
      else          src = &a1_w[((n - 5120) << 11) + k];
      dst = &W1[e];
    } else if ((idx -= NV3) < NV4) {
      size_t e = idx * 4, n = e >> 10, k = e & 1023;
      src = (n < 1024) ? &ssg_w[(n << 10) + k] : &r1_w[((n - 1024) << 10) + k];
      dst = &W2[e];
    } else if ((idx -= NV4) < NV5) {
      size_t e = idx * 4; src = &r2_w[e]; dst = &W3[e];
    } else {
      idx -= NV5;
      size_t e = idx * 4; src = &r3_w[e]; dst = &W4[e];
    }
    float4 a = *(const float4*)src;
    ushort4 o;
    o.x = f2bf(a.x); o.y = f2bf(a.y); o.z = f2bf(a.z); o.w = f2bf(a.w);
    *(ushort4*)dst = o;
  }
}

// ---------------------------------------------------------------------------
// body192: 128x192 tile, 4 waves 2x2 (per-wave 64x96, 4x6 frags), 1-barrier
// K-tile schedule, 80 KB LDS (2 blocks/CU). R12-verified best.
// ---------------------------------------------------------------------------
__device__ __forceinline__ void body192(
    unsigned short* lds, const int bid,
    const unsigned short* __restrict__ A,
    const unsigned short* __restrict__ W,
    const float* __restrict__ bWx, const float* __restrict__ bUx,
    const float* __restrict__ a1_b,
    unsigned short* __restrict__ gates,
    unsigned short* __restrict__ a_hidden)
{
  constexpr int NT  = 32;       // K = 2048
  constexpr int NTN = 32;       // 6144 / 192
  constexpr int NWG = 32 * NTN; // 1024

  const int tid  = threadIdx.x;
  const int wave = tid >> 6;
  const int lane = tid & 63;
  const int wm = wave >> 1;     // row half (64)
  const int wn = wave & 1;      // col half (96)

  const int swz = (bid & 7) * (NWG / 8) + (bid >> 3);
  const int tm = swz / NTN, tn = swz % NTN;
  const int tmB = tm * 128, tnB = tn * 192;

  const int sidx = swz1k(lane * 16);
  const int r_l  = sidx >> 6;
  const int kel  = (sidx & 63) >> 1;
  const unsigned short* pA[2][2];
  const unsigned short* pB[3][2];
#pragma unroll
  for (int rg = 0; rg < 2; ++rg)
#pragma unroll
    for (int j = 0; j < 2; ++j)
      pA[rg][j] = A + (size_t)(tmB + (wave * 2 + rg) * 16 + r_l) * K1 + j * 32 + kel;
#pragma unroll
  for (int rg = 0; rg < 3; ++rg)
#pragma unroll
    for (int j = 0; j < 2; ++j)
      pB[rg][j] = W + (size_t)(tnB + (wave * 3 + rg) * 16 + r_l) * K1 + j * 32 + kel;

#define STAGE_A(tt) do { const int p_ = (tt) & 1;                                \
    _Pragma("unroll")                                                            \
    for (int rg = 0; rg < 2; ++rg)                                               \
      _Pragma("unroll")                                                          \
      for (int j = 0; j < 2; ++j)                                                \
        gload_lds16(pA[rg][j] + (size_t)(tt) * 64,                               \
                    &lds[p_ * 20480 + ((wave * 2 + rg) * 2 + j) * 512]);         \
  } while (0)
#define STAGE_B(tt) do { const int p_ = (tt) & 1;                                \
    _Pragma("unroll")                                                            \
    for (int rg = 0; rg < 3; ++rg)                                               \
      _Pragma("unroll")                                                          \
      for (int j = 0; j < 2; ++j)                                                \
        gload_lds16(pB[rg][j] + (size_t)(tt) * 64,                               \
                    &lds[p_ * 20480 + 8192 + ((wave * 3 + rg) * 2 + j) * 512]);  \
  } while (0)

  const int loc = swz1k((lane & 15) * 64 + (lane >> 4) * 16);

  f32x4 acc[4][6];
#pragma unroll
  for (int m = 0; m < 4; ++m)
#pragma unroll
    for (int n = 0; n < 6; ++n) acc[m][n] = (f32x4){0.f, 0.f, 0.f, 0.f};

  STAGE_A(0); STAGE_B(0);   // 10 vmem ops

#define MFMA24(aV, bV) do {                                                      \
    _Pragma("unroll")                                                            \
    for (int n = 0; n < 6; ++n) {                                                \
      _Pragma("unroll")                                                          \
      for (int m = 0; m < 4; ++m)                                                \
        acc[m][n] = __builtin_amdgcn_mfma_f32_16x16x32_bf16(                     \
            aV[m], bV[n], acc[m][n], 0, 0, 0);                                   \
    } } while (0)

  const char* lchar = (const char*)lds;
  for (int t = 0; t < NT; ++t) {
    asm volatile("s_waitcnt vmcnt(0)" ::: "memory");
    __builtin_amdgcn_s_barrier();

    const char* base = lchar + (t & 1) * 40960;
    const char* bA = base + wm * 8192 + loc;
    const char* bB = base + 16384 + wn * 12288 + loc;

    bf16x8 a0[4], a1[4], b0[6], b1[6];
#pragma unroll
    for (int n = 0; n < 6; ++n) b0[n] = *(const bf16x8*)(bB + (2 * n + 0) * 1024);
#pragma unroll
    for (int m = 0; m < 4; ++m) a0[m] = *(const bf16x8*)(bA + (2 * m + 0) * 1024);
    if (t + 1 < NT) STAGE_A(t + 1);
#pragma unroll
    for (int n = 0; n < 6; ++n) b1[n] = *(const bf16x8*)(bB + (2 * n + 1) * 1024);
#pragma unroll
    for (int m = 0; m < 4; ++m) a1[m] = *(const bf16x8*)(bA + (2 * m + 1) * 1024);
    if (t + 1 < NT) STAGE_B(t + 1);

    __builtin_amdgcn_s_setprio(1);
    MFMA24(a0, b0);
    __builtin_amdgcn_s_setprio(0);
    __builtin_amdgcn_s_setprio(1);
    MFMA24(a1, b1);
    __builtin_amdgcn_s_setprio(0);
  }
#undef MFMA24
#undef STAGE_A
#undef STAGE_B

  unsigned short* slab = &lds[wave * 1536];
  const int l15 = lane & 15, lq4 = (lane >> 4) << 2;
  const int colg0 = tnB + wn * 96;
  const int rowg0 = tmB + wm * 64;
  const size_t BH = (size_t)B_DIM * H_DIM;

  float biasv[6];
  int amode[6];   // 0 sigmoid, 1 tanh, 2 relu
#pragma unroll
  for (int fn = 0; fn < 6; ++fn) {
    const int c = colg0 + fn * 16 + l15;
    if (c < 5120) {
      biasv[fn] = bWx[c] + bUx[c];
      amode[fn] = ((c >> 10) == 3) ? 1 : 0;
    } else {
      biasv[fn] = a1_b[c - 5120];
      amode[fn] = 2;
    }
  }
  __builtin_amdgcn_s_barrier();
#pragma unroll
  for (int fm = 0; fm < 4; ++fm) {
#pragma unroll
    for (int fn = 0; fn < 6; ++fn) {
      f32x4 v = acc[fm][fn];
#pragma unroll
      for (int j = 0; j < 4; ++j) {
        const int row = lq4 + j;
        const float xv = v[j] + biasv[fn];
        const float res = (amode[fn] == 1) ? fast_tanh(xv)
                         : (amode[fn] == 0) ? fast_sigmoid(xv)
                         : fmaxf(xv, 0.f);
        const int byte = (row * 192 + (fn * 16 + l15) * 2) ^ (((row >> 2) & 1) << 5);
        slab[byte >> 1] = f2bf(res);
      }
    }
    asm volatile("s_waitcnt lgkmcnt(0)" ::: "memory");
    __builtin_amdgcn_sched_barrier(0);
#pragma unroll
    for (int p = 0; p < 3; ++p) {
      const int id = p * 64 + lane;
      const int row = id / 12, cc = id - row * 12;
      const int byte = (row * 192 + cc * 16) ^ (((row >> 2) & 1) << 5);
      bf16x8 pk = *(const bf16x8*)((const char*)slab + byte);
      const int col = colg0 + cc * 8;
      const size_t r = (size_t)(rowg0 + fm * 16 + row);
      unsigned short* dst;
      if (col < 5120) dst = gates + (size_t)(col >> 10) * BH + r * 1024 + (col & 1023);
      else            dst = a_hidden + r * 1024 + (col - 5120);
      *(bf16x8*)dst = pk;
    }
    asm volatile("s_waitcnt lgkmcnt(0)" ::: "memory");
    __builtin_amdgcn_sched_barrier(0);
  }
}

// ---------------------------------------------------------------------------
// gemm_body<NT, MODE=1>: 128x128 structure for ssg+r1 (R11-verified).
// ---------------------------------------------------------------------------
template <int NT, int MODE>
__device__ __forceinline__ void gemm_body(
    unsigned short* lds, const int bid,
    const unsigned short* __restrict__ A0,
    const unsigned short* __restrict__ A1,
    const unsigned short* __restrict__ W,
    const float* __restrict__ b0, const float* __restrict__ b1,
    void* __restrict__ out0, void* __restrict__ out1)
{
  constexpr int KDIM = NT * 64;
  constexpr int NTN  = 16;
  constexpr int NWG  = 32 * NTN;

  const int tid  = threadIdx.x;
  const int wave = tid >> 6;
  const int lane = tid & 63;
  const int wm = wave >> 1;
  const int wn = wave & 1;

  const int swz = (bid & 7) * (NWG / 8) + (bid >> 3);
  const int tm = swz / NTN, tn = swz % NTN;
  const int tmB = tm * 128, tnB = tn * 128;

  const unsigned short* Abase = A0;
  int lda = 1024;
  if (tn >= 8) { Abase = A1; lda = 2048; }

  const int sidx = swz1k(lane * 16);
  const int r_l  = sidx >> 6;
  const int kel  = (sidx & 63) >> 1;
  const unsigned short* pA[2][2];
  const unsigned short* pB[2][2];
#pragma unroll
  for (int rg = 0; rg < 2; ++rg)
#pragma unroll
    for (int j = 0; j < 2; ++j) {
      const int rr = wave * 32 + rg * 16 + r_l;
      const int kk0 = j * 32 + kel;
      pA[rg][j] = Abase + (size_t)(tmB + rr) * lda + kk0;
      pB[rg][j] = W + (size_t)(tnB + rr) * KDIM + kk0;
    }

#define STAGE_A(tt) do { const int p_ = (tt) & 1;                                \
    _Pragma("unroll")                                                            \
    for (int rg = 0; rg < 2; ++rg)                                               \
      _Pragma("unroll")                                                          \
      for (int j = 0; j < 2; ++j)                                                \
        gload_lds16(pA[rg][j] + (size_t)(tt) * 64,                               \
                    &lds[p_ * 16384 + ((wave * 2 + rg) * 2 + j) * 512]);         \
  } while (0)
#define STAGE_B(tt) do { const int p_ = (tt) & 1;                                \
    _Pragma("unroll")                                                            \
    for (int rg = 0; rg < 2; ++rg)                                               \
      _Pragma("unroll")                                                          \
      for (int j = 0; j < 2; ++j)                                                \
        gload_lds16(pB[rg][j] + (size_t)(tt) * 64,                               \
                    &lds[p_ * 16384 + 8192 + ((wave * 2 + rg) * 2 + j) * 512]);  \
  } while (0)

  const int loc = swz1k((lane & 15) * 64 + (lane >> 4) * 16);

  f32x4 acc[4][4];
#pragma unroll
  for (int m = 0; m < 4; ++m)
#pragma unroll
    for (int n = 0; n < 4; ++n) acc[m][n] = (f32x4){0.f, 0.f, 0.f, 0.f};

  STAGE_A(0); STAGE_B(0);

#define MFMA16(aV, bV) do {                                                      \
    _Pragma("unroll")                                                            \
    for (int n = 0; n < 4; ++n) {                                                \
      _Pragma("unroll")                                                          \
      for (int m = 0; m < 4; ++m)                                                \
        acc[m][n] = __builtin_amdgcn_mfma_f32_16x16x32_bf16(                     \
            aV[m], bV[n], acc[m][n], 0, 0, 0);                                   \
    } } while (0)

  const char* lchar = (const char*)lds;
  for (int t = 0; t < NT; ++t) {
    asm volatile("s_waitcnt vmcnt(0)" ::: "memory");
    __builtin_amdgcn_s_barrier();

    const char* base = lchar + (t & 1) * 32768;
    const char* bA = base + wm * 8192 + loc;
    const char* bB = base + 16384 + wn * 8192 + loc;

    bf16x8 a0[4], a1[4], b0v[4], b1v[4];
#pragma unroll
    for (int n = 0; n < 4; ++n) b0v[n] = *(const bf16x8*)(bB + (2 * n + 0) * 1024);
#pragma unroll
    for (int m = 0; m < 4; ++m) a0[m] = *(const bf16x8*)(bA + (2 * m + 0) * 1024);
    if (t + 1 < NT) STAGE_A(t + 1);
#pragma unroll
    for (int n = 0; n < 4; ++n) b1v[n] = *(const bf16x8*)(bB + (2 * n + 1) * 1024);
#pragma unroll
    for (int m = 0; m < 4; ++m) a1[m] = *(const bf16x8*)(bA + (2 * m + 1) * 1024);
    if (t + 1 < NT) STAGE_B(t + 1);

    __builtin_amdgcn_s_setprio(1);
    MFMA16(a0, b0v);
    __builtin_amdgcn_s_setprio(0);
    __builtin_amdgcn_s_setprio(1);
    MFMA16(a1, b1v);
    __builtin_amdgcn_s_setprio(0);
  }
#undef MFMA16
#undef STAGE_A
#undef STAGE_B

  const int l15 = lane & 15, lq4 = (lane >> 4) << 2;
  const int rowg0 = tmB + wm * 64;

  if (tn < 8) {
    const int col0 = tn * 128 + wn * 64;
#pragma unroll
    for (int fn = 0; fn < 4; ++fn) {
      const int col = col0 + fn * 16 + l15;
      const float bias = b0[col];
#pragma unroll
      for (int fm = 0; fm < 4; ++fm) {
        f32x4 v = acc[fm][fn];
#pragma unroll
        for (int j = 0; j < 4; ++j) {
          const int r = rowg0 + fm * 16 + lq4 + j;
          ((float*)out0)[(size_t)r * 1024 + col] = v[j] + bias;
        }
      }
    }
    return;
  }

  unsigned short* slab = &lds[wave * 1024];
  const int lr8 = lane >> 3, lc8 = lane & 7;
  const int colg0 = (tn - 8) * 128 + wn * 64;
  unsigned short* outbase = (unsigned short*)out1;
  float biasv[4];
#pragma unroll
  for (int fn = 0; fn < 4; ++fn) biasv[fn] = b1[colg0 + fn * 16 + l15];
  __builtin_amdgcn_s_barrier();
#pragma unroll
  for (int fm = 0; fm < 4; ++fm) {
#pragma unroll
    for (int fn = 0; fn < 4; ++fn) {
      f32x4 v = acc[fm][fn];
#pragma unroll
      for (int j = 0; j < 4; ++j) {
        const int row = lq4 + j;
        const float res = fmaxf(v[j] + biasv[fn], 0.f);
        const int colb = ((fn * 16 + l15) * 2) ^ (((row >> 2) & 3) << 5);
        slab[(row * 128 + colb) >> 1] = f2bf(res);
      }
    }
    asm volatile("s_waitcnt lgkmcnt(0)" ::: "memory");
    __builtin_amdgcn_sched_barrier(0);
#pragma unroll
    for (int rd = 0; rd < 2; ++rd) {
      const int row = rd * 8 + lr8;
      const int cb = (lc8 * 16) ^ (((row >> 2) & 3) << 5);
      bf16x8 pk = *(const bf16x8*)((const char*)slab + row * 128 + cb);
      const size_t r = (size_t)(rowg0 + fm * 16 + row);
      *(bf16x8*)&outbase[r * 1024 + colg0 + lc8 * 8] = pk;
    }
    asm volatile("s_waitcnt lgkmcnt(0)" ::: "memory");
    __builtin_amdgcn_sched_barrier(0);
  }
}

// ---------------------------------------------------------------------------
// merged big GEMM: blocks [0,1024) = gates+a_hidden (128x192); [1024,1536) =
// ssg+r1 (128x128). 80 KB shared -> 2 blocks/CU.
// ---------------------------------------------------------------------------
__global__ __launch_bounds__(256, 2) void gemm_big(
    const unsigned short* __restrict__ combined,
    const unsigned short* __restrict__ ssg_in,
    const unsigned short* __restrict__ W1,
    const unsigned short* __restrict__ W2,
    const float* __restrict__ bWx, const float* __restrict__ bUx,
    const float* __restrict__ a1_b,
    const float* __restrict__ ssg_b, const float* __restrict__ r1_b,
    unsigned short* __restrict__ gates,
    unsigned short* __restrict__ a_hidden,
    float* __restrict__ ssg_out,
    unsigned short* __restrict__ r1)
{
  __shared__ unsigned short lds[40960];  // 80 KiB
  const int bid = blockIdx.x;
  if (bid < 1024) {
    body192(lds, bid, combined, W1, bWx, bUx, a1_b, gates, a_hidden);
  } else {
    gemm_body<16, 1>(lds, bid - 1024, ssg_in, combined + 1024, W2,
                     ssg_b, r1_b, ssg_out, r1);
  }
}

// ---------------------------------------------------------------------------
// gemm_small64<MODE>: 64x128 tile, BK=64, 48 KB LDS, 3 blocks/CU, grid 512.
// MODE 2: relu -> bf16 out.  MODE 3: bf16 out (no relu) — residual is an
// internal intermediate now stored bf16 (saves 8 MB write + 8 MB read).
// ---------------------------------------------------------------------------
template <int MODE>
__global__ __launch_bounds__(256, 3) void gemm_small64(
    const unsigned short* __restrict__ A,
    const unsigned short* __restrict__ W,
    const float* __restrict__ bias,
    unsigned short* __restrict__ out)
{
  __shared__ unsigned short lds[24576];  // 48 KiB
  constexpr int NT = 16;                 // K = 1024

  const int tid  = threadIdx.x;
  const int wave = tid >> 6;
  const int lane = tid & 63;
  const int wm = wave >> 1;   // row half (32)
  const int wn = wave & 1;    // col half (64)

  const int bid = blockIdx.x;
  const int swz = (bid & 7) * 64 + (bid >> 3);   // NWG = 512, bijective
  const int tm = swz >> 3, tn = swz & 7;
  const int tmB = tm * 64, tnB = tn * 128;

  const int sidx = swz1k(lane * 16);
  const int r_l  = sidx >> 6;
  const int kel  = (sidx & 63) >> 1;
  const unsigned short* pA[2];
  const unsigned short* pB[2][2];
#pragma unroll
  for (int j = 0; j < 2; ++j)
    pA[j] = A + (size_t)(tmB + wave * 16 + r_l) * 1024 + j * 32 + kel;
#pragma unroll
  for (int rg = 0; rg < 2; ++rg)
#pragma unroll
    for (int j = 0; j < 2; ++j)
      pB[rg][j] = W + (size_t)(tnB + (wave * 2 + rg) * 16 + r_l) * 1024 + j * 32 + kel;

#define STAGE_A(tt) do { const int p_ = (tt) & 1;                                \
    _Pragma("unroll")                                                            \
    for (int j = 0; j < 2; ++j)                                                  \
      gload_lds16(pA[j] + (size_t)(tt) * 64,                                     \
                  &lds[p_ * 12288 + (wave * 2 + j) * 512]);                      \
  } while (0)
#define STAGE_B(tt) do { const int p_ = (tt) & 1;                                \
    _Pragma("unroll")                                                            \
    for (int rg = 0; rg < 2; ++rg)                                               \
      _Pragma("unroll")                                                          \
      for (int j = 0; j < 2; ++j)                                                \
        gload_lds16(pB[rg][j] + (size_t)(tt) * 64,                               \
                    &lds[p_ * 12288 + 4096 + ((wave * 2 + rg) * 2 + j) * 512]);  \
  } while (0)

  const int loc = swz1k((lane & 15) * 64 + (lane >> 4) * 16);

  f32x4 acc[2][4];
#pragma unroll
  for (int m = 0; m < 2; ++m)
#pragma unroll
    for (int n = 0; n < 4; ++n) acc[m][n] = (f32x4){0.f, 0.f, 0.f, 0.f};

  STAGE_A(0); STAGE_B(0);   // 6 vmem ops

  const char* lchar = (const char*)lds;
  for (int t = 0; t < NT; ++t) {
    asm volatile("s_waitcnt vmcnt(0)" ::: "memory");
    __builtin_amdgcn_s_barrier();

    const char* base = lchar + (t & 1) * 24576;
    const char* bA = base + wm * 4096 + loc;
    const char* bB = base + 8192 + wn * 8192 + loc;

    bf16x8 a0[2], a1[2], b0[4], b1[4];
#pragma unroll
    for (int n = 0; n < 4; ++n) b0[n] = *(const bf16x8*)(bB + (2 * n + 0) * 1024);
#pragma unroll
    for (int m = 0; m < 2; ++m) a0[m] = *(const bf16x8*)(bA + (2 * m + 0) * 1024);
    if (t + 1 < NT) STAGE_A(t + 1);
#pragma unroll
    for (int n = 0; n < 4; ++n) b1[n] = *(const bf16x8*)(bB + (2 * n + 1) * 1024);
#pragma unroll
    for (int m = 0; m < 2; ++m) a1[m] = *(const bf16x8*)(bA + (2 * m + 1) * 1024);
    if (t + 1 < NT) STAGE_B(t + 1);

    __builtin_amdgcn_s_setprio(1);
#pragma unroll
    for (int n = 0; n < 4; ++n)
#pragma unroll
      for (int m = 0; m < 2; ++m)
        acc[m][n] = __builtin_amdgcn_mfma_f32_16x16x32_bf16(a0[m], b0[n], acc[m][n], 0, 0, 0);
    __builtin_amdgcn_s_setprio(0);
    __builtin_amdgcn_s_setprio(1);
#pragma unroll
    for (int n = 0; n < 4; ++n)
#pragma unroll
      for (int m = 0; m < 2; ++m)
        acc[m][n] = __builtin_amdgcn_mfma_f32_16x16x32_bf16(a1[m], b1[n], acc[m][n], 0, 0, 0);
    __builtin_amdgcn_s_setprio(0);
  }
#undef STAGE_A
#undef STAGE_B

  const int l15 = lane & 15, lq4 = (lane >> 4) << 2;
  const int rowg0 = tmB + wm * 32;

  // bf16 output via per-wave slab restage (MODE 2: relu; MODE 3: identity)
  unsigned short* slab = &lds[wave * 1024];
  const int lr8 = lane >> 3, lc8 = lane & 7;
  const int colg0 = tnB + wn * 64;
  float biasv[4];
#pragma unroll
  for (int fn = 0; fn < 4; ++fn) biasv[fn] = bias[colg0 + fn * 16 + l15];
  __builtin_amdgcn_s_barrier();
#pragma unroll
  for (int fm = 0; fm < 2; ++fm) {
#pragma unroll
    for (int fn = 0; fn < 4; ++fn) {
      f32x4 v = acc[fm][fn];
#pragma unroll
      for (int j = 0; j < 4; ++j) {
        const int row = lq4 + j;
        const float xv = v[j] + biasv[fn];
        const float res = (MODE == 2) ? fmaxf(xv, 0.f) : xv;
        const int colb = ((fn * 16 + l15) * 2) ^ (((row >> 2) & 3) << 5);
        slab[(row * 128 + colb) >> 1] = f2bf(res);
      }
    }
    asm volatile("s_waitcnt lgkmcnt(0)" ::: "memory");
    __builtin_amdgcn_sched_barrier(0);
#pragma unroll
    for (int rd = 0; rd < 2; ++rd) {
      const int row = rd * 8 + lr8;
      const int cb = (lc8 * 16) ^ (((row >> 2) & 3) << 5);
      bf16x8 pk = *(const bf16x8*)((const char*)slab + row * 128 + cb);
      const size_t r = (size_t)(rowg0 + fm * 16 + row);
      *(bf16x8*)&out[r * 1024 + colg0 + lc8 * 8] = pk;
    }
    asm volatile("s_waitcnt lgkmcnt(0)" ::: "memory");
    __builtin_amdgcn_sched_barrier(0);
  }
}

// ---------------------------------------------------------------------------
// final fused: per-row alpha (4-wave reduce) + vec4 elementwise cell update.
// residual now read as bf16.
// ---------------------------------------------------------------------------
__global__ __launch_bounds__(256) void final_fused(
    const unsigned short* __restrict__ gates,
    const float* __restrict__ c_prev,
    const unsigned short* __restrict__ a_hidden,
    const float* __restrict__ a2_w, const float* __restrict__ a2_b,
    const unsigned short* __restrict__ residual,
    const float* __restrict__ ssg_new,
    float* __restrict__ h_out, float* __restrict__ c_out)
{
  __shared__ float red[5];
  const int r = blockIdx.x;
  const int tid = threadIdx.x;
  const size_t BH = (size_t)B_DIM * H_DIM;

  {
    ushort4 u = *(const ushort4*)&a_hidden[(size_t)r * 1024 + tid * 4];
    float4 w = *(const float4*)&a2_w[tid * 4];
    float s = bf2f(u.x) * w.x + bf2f(u.y) * w.y + bf2f(u.z) * w.z + bf2f(u.w) * w.w;
#pragma unroll
    for (int off = 32; off; off >>= 1) s += __shfl_xor(s, off);
    if ((tid & 63) == 0) red[tid >> 6] = s;
  }
  __syncthreads();
  if (tid == 0)
    red[4] = fast_sigmoid(red[0] + red[1] + red[2] + red[3] + a2_b[0]);
  __syncthreads();
  const float al = red[4];

  const size_t e = (size_t)r * 1024 + tid * 4;
  ushort4 iu = *(const ushort4*)&gates[e];
  ushort4 fu = *(const ushort4*)&gates[BH + e];
  ushort4 ou = *(const ushort4*)&gates[2 * BH + e];
  ushort4 cu = *(const ushort4*)&gates[3 * BH + e];
  ushort4 su = *(const ushort4*)&gates[4 * BH + e];
  float4 cp = *(const float4*)&c_prev[e];
  ushort4 ru = *(const ushort4*)&residual[e];
  float4 sg = *(const float4*)&ssg_new[e];
  float4 ho, co;
  co.x = bf2f(fu.x) * cp.x + bf2f(iu.x) * bf2f(cu.x) * bf2f(su.x) * al * sg.x + bf2f(ru.x);
  co.y = bf2f(fu.y) * cp.y + bf2f(iu.y) * bf2f(cu.y) * bf2f(su.y) * al * sg.y + bf2f(ru.y);
  co.z = bf2f(fu.z) * cp.z + bf2f(iu.z) * bf2f(cu.z) * bf2f(su.z) * al * sg.z + bf2f(ru.z);
  co.w = bf2f(fu.w) * cp.w + bf2f(iu.w) * bf2f(cu.w) * bf2f(su.w) * al * sg.w + bf2f(ru.w);
  ho.x = bf2f(ou.x) * fast_tanh(co.x);
  ho.y = bf2f(ou.y) * fast_tanh(co.y);
  ho.z = bf2f(ou.z) * fast_tanh(co.z);
  ho.w = bf2f(ou.w) * fast_tanh(co.w);
  *(float4*)&h_out[e] = ho;
  *(float4*)&c_out[e] = co;
}

// ---------------------------------------------------------------------------
extern "C" void kernel_launch(void* const* d_in, const int* in_sizes, int n_in,
                              void* d_out, int out_size, void* d_ws, size_t ws_size,
                              hipStream_t stream)
{
  (void)in_sizes; (void)n_in; (void)out_size; (void)ws_size;
  const float* x         = (const float*)d_in[0];
  const float* h_prev    = (const float*)d_in[1];
  const float* c_prev    = (const float*)d_in[2];
  const float* ssg_state = (const float*)d_in[3];
  const float* Wx        = (const float*)d_in[4];
  const float* bWx       = (const float*)d_in[5];
  const float* Ux        = (const float*)d_in[6];
  const float* bUx       = (const float*)d_in[7];
  const float* a1_w      = (const float*)d_in[8];
  const float* a1_b      = (const float*)d_in[9];
  const float* a2_w      = (const float*)d_in[10];
  const float* a2_b      = (const float*)d_in[11];
  const float* r1_w      = (const float*)d_in[12];
  const float* r1_b      = (const float*)d_in[13];
  const float* r2_w      = (const float*)d_in[14];
  const float* r2_b      = (const float*)d_in[15];
  const float* r3_w      = (const float*)d_in[16];
  const float* r3_b      = (const float*)d_in[17];
  const float* ssg_w     = (const float*)d_in[18];
  const float* ssg_b     = (const float*)d_in[19];

  char* ws = (char*)d_ws;
  unsigned short* combined = (unsigned short*)(ws);               // 16,777,216
  unsigned short* ssg_in   = (unsigned short*)(ws + 16777216);    //  8,388,608
  unsigned short* W1       = (unsigned short*)(ws + 33554432);    // 25,165,824
  unsigned short* W2       = (unsigned short*)(ws + 58720256);    //  4,194,304
  unsigned short* W3       = (unsigned short*)(ws + 62914560);    //  2,097,152
  unsigned short* W4       = (unsigned short*)(ws + 65011712);    //  2,097,152
  unsigned short* gates    = (unsigned short*)(ws + 67108864);    // 41,943,040
  unsigned short* a_hidden = (unsigned short*)(ws + 109051904);   //  8,388,608
  unsigned short* r1       = (unsigned short*)(ws + 117456896);   //  8,388,608
  unsigned short* r2       = (unsigned short*)(ws + 125845504);   //  8,388,608
  unsigned short* residual = (unsigned short*)(ws + 134234112);   //  8,388,608 (bf16)

  float* h_out   = (float*)d_out;
  float* c_out   = h_out + (size_t)B_DIM * H_DIM;
  float* ssg_out = c_out + (size_t)B_DIM * H_DIM;

  prep_kernel<<<4096, 256, 0, stream>>>(x, h_prev, ssg_state, Wx, Ux, a1_w,
                                        ssg_w, r1_w, r2_w, r3_w,
                                        combined, ssg_in, W1, W2, W3, W4);

  gemm_big<<<1536, 256, 0, stream>>>(
      combined, ssg_in, W1, W2, bWx, bUx, a1_b, ssg_b, r1_b,
      gates, a_hidden, ssg_out, r1);

  gemm_small64<2><<<512, 256, 0, stream>>>(r1, W3, r2_b, r2);

  gemm_small64<3><<<512, 256, 0, stream>>>(r2, W4, r3_b, residual);

  final_fused<<<B_DIM, 256, 0, stream>>>(
      gates, c_prev, a_hidden, a2_w, a2_b, residual, ssg_out, h_out, c_out);
}